// Round 9
// baseline (450.466 us; speedup 1.0000x reference)
//
#include <hip/hip_runtime.h>

#define BN_EPS 1e-5f
#define AGG_BLOCKS 2048
#define COLRED_BLOCKS 64   // AGG_BLOCKS / COLRED_BLOCKS rows each
#define SSTAT_BLOCKS 64
#define NREP 8             // histogram replicas for edge_prep atomics
#define GEMM_BLOCKS 1024

typedef __attribute__((ext_vector_type(8))) short short8;
typedef __attribute__((ext_vector_type(4))) float f32x4;

#define MFMA16(a, b, c) __builtin_amdgcn_mfma_f32_16x16x32_bf16(a, b, c, 0, 0, 0)

__device__ __forceinline__ short f2bf(float f) {
    unsigned int u = __float_as_uint(f);
    u = (u + 0x7FFFu + ((u >> 16) & 1u)) >> 16;
    return (short)u;
}
__device__ __forceinline__ float bf2f(short s) {
    return __uint_as_float(((unsigned int)(unsigned short)s) << 16);
}
__device__ __forceinline__ float lo16f(unsigned int u) { return __uint_as_float(u << 16); }
__device__ __forceinline__ float hi16f(unsigned int u) { return __uint_as_float(u & 0xffff0000u); }

// ================= GEMM device body (register-resident W, MFMA, 2-deep pipeline) ========
// ASRC 0: A = fp32 raw (x)                      -> C bf16 plane
// ASRC 1: A = bf16 raw + BN+ReLU in-register    -> C bf16 plane
// ASRC 2: A = fp32 + BN+ReLU + hi/lo split; 3-pass MFMA; bias+PWL epilogue -> C fp32
template <int ASRC>
__device__ __forceinline__ void gemm_body(
    const void* __restrict__ Ain, const float* __restrict__ W, void* __restrict__ Cout,
    const float* __restrict__ scale, const float* __restrict__ shift,
    const float* __restrict__ bias,
    const int* __restrict__ pdx, const int* __restrict__ pgx,
    const float* __restrict__ vdc, const float* __restrict__ vgc,
    const float* __restrict__ tabd, const float* __restrict__ tabg,
    int n, int bid, int nb) {
    constexpr bool FINAL = (ASRC == 2);
    const int lane = threadIdx.x & 63;
    const int wave = threadIdx.x >> 6;
    const int l15 = lane & 15, lg = lane >> 4;
    const int cbase = wave * 32;

    short8 wh[4][2], wl[4][2];
#pragma unroll
    for (int kt = 0; kt < 4; ++kt) {
#pragma unroll
        for (int cf = 0; cf < 2; ++cf) {
            int col = cbase + 16 * cf + l15;
            short8 hh, ll;
#pragma unroll
            for (int e = 0; e < 8; ++e) {
                float wv = W[(32 * kt + 8 * lg + e) * 128 + col];
                short hs = f2bf(wv);
                hh[e] = hs;
                if (FINAL) ll[e] = f2bf(wv - bf2f(hs));
            }
            wh[kt][cf] = hh;
            if (FINAL) wl[kt][cf] = ll;
        }
    }

    float4 scr[4][2], shr[4][2];
    if (ASRC == 1) {
#pragma unroll
        for (int kt = 0; kt < 4; ++kt) {
            scr[kt][0] = *(const float4*)&scale[32 * kt + 8 * lg];
            scr[kt][1] = *(const float4*)&scale[32 * kt + 8 * lg + 4];
            shr[kt][0] = *(const float4*)&shift[32 * kt + 8 * lg];
            shr[kt][1] = *(const float4*)&shift[32 * kt + 8 * lg + 4];
        }
    }

    float b0 = 0.f, b1 = 0.f;
    if (FINAL) { b0 = bias[cbase + l15]; b1 = bias[cbase + 16 + l15]; }

    const int ntiles = (n + 15) >> 4;

    short8 ah[4], al[4], nh[4], nl[4];
    auto loada = [&](int t, short8* H, short8* L) {
        int row = t * 16 + l15;
        if (row >= n) row = n - 1;
        if (ASRC == 0) {
            const float* p = (const float*)Ain + (size_t)row * 128 + 8 * lg;
#pragma unroll
            for (int kt = 0; kt < 4; ++kt) {
                float4 u = *(const float4*)(p + 32 * kt);
                float4 v = *(const float4*)(p + 32 * kt + 4);
                short8 h;
                h[0] = f2bf(u.x); h[1] = f2bf(u.y); h[2] = f2bf(u.z); h[3] = f2bf(u.w);
                h[4] = f2bf(v.x); h[5] = f2bf(v.y); h[6] = f2bf(v.z); h[7] = f2bf(v.w);
                H[kt] = h;
            }
        } else if (ASRC == 1) {
            const unsigned short* p = (const unsigned short*)Ain + (size_t)row * 128 + 8 * lg;
#pragma unroll
            for (int kt = 0; kt < 4; ++kt) {
                short8 s = *(const short8*)(p + 32 * kt);
                short8 h;
#pragma unroll
                for (int e = 0; e < 8; ++e) {
                    float sc = (e < 4) ? ((const float*)&scr[kt][0])[e] : ((const float*)&scr[kt][1])[e - 4];
                    float sh = (e < 4) ? ((const float*)&shr[kt][0])[e] : ((const float*)&shr[kt][1])[e - 4];
                    float f = fmaxf(0.0f, fmaf(bf2f(s[e]), sc, sh));
                    h[e] = f2bf(f);
                }
                H[kt] = h;
            }
        } else {
            const float* p = (const float*)Ain + (size_t)row * 128 + 8 * lg;
#pragma unroll
            for (int kt = 0; kt < 4; ++kt) {
                float4 u = *(const float4*)(p + 32 * kt);
                float4 v = *(const float4*)(p + 32 * kt + 4);
                float4 sa = *(const float4*)&scale[32 * kt + 8 * lg];
                float4 sb = *(const float4*)&scale[32 * kt + 8 * lg + 4];
                float4 ta = *(const float4*)&shift[32 * kt + 8 * lg];
                float4 tb = *(const float4*)&shift[32 * kt + 8 * lg + 4];
                float f[8];
                f[0] = fmaxf(0.f, fmaf(u.x, sa.x, ta.x));
                f[1] = fmaxf(0.f, fmaf(u.y, sa.y, ta.y));
                f[2] = fmaxf(0.f, fmaf(u.z, sa.z, ta.z));
                f[3] = fmaxf(0.f, fmaf(u.w, sa.w, ta.w));
                f[4] = fmaxf(0.f, fmaf(v.x, sb.x, tb.x));
                f[5] = fmaxf(0.f, fmaf(v.y, sb.y, tb.y));
                f[6] = fmaxf(0.f, fmaf(v.z, sb.z, tb.z));
                f[7] = fmaxf(0.f, fmaf(v.w, sb.w, tb.w));
                short8 h, l;
#pragma unroll
                for (int e = 0; e < 8; ++e) {
                    short hs = f2bf(f[e]);
                    h[e] = hs;
                    l[e] = f2bf(f[e] - bf2f(hs));
                }
                H[kt] = h;
                L[kt] = l;
            }
        }
    };

    int tile = bid;
    if (tile < ntiles) loada(tile, ah, al);
    for (; tile < ntiles; tile += nb) {
        int nx = tile + nb;
        if (nx < ntiles) loada(nx, nh, nl);   // 2-deep pipeline (all ASRC)

        f32x4 acc0 = {0.f, 0.f, 0.f, 0.f};
        f32x4 acc1 = {0.f, 0.f, 0.f, 0.f};
#pragma unroll
        for (int kt = 0; kt < 4; ++kt) {
            acc0 = MFMA16(ah[kt], wh[kt][0], acc0);
            acc1 = MFMA16(ah[kt], wh[kt][1], acc1);
        }
        if (FINAL) {
#pragma unroll
            for (int kt = 0; kt < 4; ++kt) {
                acc0 = MFMA16(al[kt], wh[kt][0], acc0);
                acc1 = MFMA16(al[kt], wh[kt][1], acc1);
            }
#pragma unroll
            for (int kt = 0; kt < 4; ++kt) {
                acc0 = MFMA16(ah[kt], wl[kt][0], acc0);
                acc1 = MFMA16(ah[kt], wl[kt][1], acc1);
            }
        }

        int rbase = tile * 16;
        if constexpr (!FINAL) {
            unsigned short* C = (unsigned short*)Cout;
#pragma unroll
            for (int r = 0; r < 4; ++r) {
                int row = rbase + lg * 4 + r;
                if (row < n) {
                    C[(size_t)row * 128 + cbase + l15]      = (unsigned short)f2bf(acc0[r]);
                    C[(size_t)row * 128 + cbase + 16 + l15] = (unsigned short)f2bf(acc1[r]);
                }
            }
        } else {
            float* C = (float*)Cout;
#pragma unroll
            for (int r = 0; r < 4; ++r) {
                int row = rbase + lg * 4 + r;
                int rc = row < n ? row : n - 1;
                float vd = vdc[rc], vg = vgc[rc];
                int pd = pdx[rc] * 256, pg = pgx[rc] * 256;
                int c0 = cbase + l15, c1 = cbase + 16 + l15;
                float v0 = acc0[r] + b0, v1 = acc1[r] + b1;
                v0 = fmaf(tabd[pd + c0], vd, v0) + tabd[pd + 128 + c0];
                v1 = fmaf(tabd[pd + c1], vd, v1) + tabd[pd + 128 + c1];
                v0 = fmaf(tabg[pg + c0], vg, v0) + tabg[pg + 128 + c0];
                v1 = fmaf(tabg[pg + c1], vg, v1) + tabg[pg + 128 + c1];
                if (row < n) {
                    C[(size_t)row * 128 + c0] = v0;
                    C[(size_t)row * 128 + c1] = v1;
                }
            }
        }
#pragma unroll
        for (int kt = 0; kt < 4; ++kt) {
            ah[kt] = nh[kt];
            if (FINAL) al[kt] = nl[kt];
        }
    }
}

template <int ASRC>
__global__ __launch_bounds__(256) void gemm_mfma(
    const void* __restrict__ Ain, const float* __restrict__ W, void* __restrict__ Cout,
    const float* __restrict__ scale, const float* __restrict__ shift,
    const float* __restrict__ bias,
    const int* __restrict__ pdx, const int* __restrict__ pgx,
    const float* __restrict__ vdc, const float* __restrict__ vgc,
    const float* __restrict__ tabd, const float* __restrict__ tabg, int n) {
    gemm_body<ASRC>(Ain, W, Cout, scale, shift, bias, pdx, pgx, vdc, vgc, tabd, tabg,
                    n, blockIdx.x, gridDim.x);
}

// ================= MEGA1: gemm1 (blocks 0..GB) + edge_prep + scalar_stats =================
__global__ __launch_bounds__(256) void k_mega1(
    const int* __restrict__ dst, const float* __restrict__ ew,
    unsigned long long* __restrict__ pack64, unsigned short* __restrict__ rank,
    int e, int n,
    const float* __restrict__ x, const float* __restrict__ W1, void* __restrict__ planeB,
    const float* __restrict__ df, const float* __restrict__ gf,
    float4* __restrict__ partial4, int nbE) {
    if (blockIdx.x < GEMM_BLOCKS) {
        gemm_body<0>(x, W1, planeB, nullptr, nullptr, nullptr,
                     nullptr, nullptr, nullptr, nullptr, nullptr, nullptr,
                     n, blockIdx.x, GEMM_BLOCKS);
        return;
    }
    int bid = blockIdx.x - GEMM_BLOCKS;
    if (bid < nbE) {
        int i = bid * 256 + threadIdx.x;
        if (i < e) {
            int rep = bid & (NREP - 1);
            int d = dst[i];
            unsigned long long fx = (unsigned long long)(ew[i] * 1.099511627776e12f);  // 2^40
            unsigned long long old = atomicAdd(&pack64[(size_t)rep * n + d], (1ull << 54) | fx);
            rank[i] = (unsigned short)(old >> 54);
        }
        return;
    }
    // scalar-stats role
    int sb = bid - nbE;
    float sd = 0, sd2 = 0, sg = 0, sg2 = 0;
    for (int i = sb * 256 + threadIdx.x; i < n; i += SSTAT_BLOCKS * 256) {
        float a = df[i], b = gf[i];
        sd += a; sd2 += a * a; sg += b; sg2 += b * b;
    }
    for (int off = 32; off > 0; off >>= 1) {
        sd  += __shfl_down(sd, off, 64);
        sd2 += __shfl_down(sd2, off, 64);
        sg  += __shfl_down(sg, off, 64);
        sg2 += __shfl_down(sg2, off, 64);
    }
    __shared__ float4 wred[4];
    int lane = threadIdx.x & 63, wave = threadIdx.x >> 6;
    if (lane == 0) { float4 v; v.x = sd; v.y = sd2; v.z = sg; v.w = sg2; wred[wave] = v; }
    __syncthreads();
    if (threadIdx.x == 0) {
        float4 a = wred[0], b = wred[1], c = wred[2], d = wred[3];
        float4 o;
        o.x = a.x + b.x + c.x + d.x;
        o.y = a.y + b.y + c.y + d.y;
        o.z = a.z + b.z + c.z + d.z;
        o.w = a.w + b.w + c.w + d.w;
        partial4[sb] = o;
    }
}

// ---------------- scan: combine replicas -> counts/dinv/base, block-scan offs ----------------
__global__ void k_scan1(const unsigned long long* __restrict__ pack64,
                        int* counts, int* offs, int* bsums, float* dinv,
                        int* __restrict__ base, int n) {
    __shared__ int tmp[256];
    int t = threadIdx.x;
    int i = blockIdx.x * 256 + t;
    int v = 0;
    if (i < n) {
        unsigned long long degsum = 0;
        int c = 0;
#pragma unroll
        for (int r = 0; r < NREP; ++r) {
            unsigned long long p = pack64[(size_t)r * n + i];
            base[(size_t)r * n + i] = c;
            c += (int)(p >> 54);
            degsum += (p & ((1ull << 54) - 1ull));
        }
        float deg = 1.0f + (float)degsum * 9.094947017729282e-13f; // 2^-40
        dinv[i] = rsqrtf(deg);
        counts[i] = c;
        v = c;
    }
    tmp[t] = v;
    __syncthreads();
    for (int d = 1; d < 256; d <<= 1) {
        int add = (t >= d) ? tmp[t - d] : 0;
        __syncthreads();
        tmp[t] += add;
        __syncthreads();
    }
    if (i < n) offs[i] = tmp[t] - v;
    if (t == 255) bsums[blockIdx.x] = tmp[255];
}

__global__ void k_scan2(int* bsums, int nb) {
    __shared__ int tmp[512];
    int t = threadIdx.x;
    int v = (t < nb) ? bsums[t] : 0;
    tmp[t] = v;
    __syncthreads();
    for (int d = 1; d < 512; d <<= 1) {
        int add = (t >= d) ? tmp[t - d] : 0;
        __syncthreads();
        tmp[t] += add;
        __syncthreads();
    }
    if (t < nb) bsums[t] = tmp[t] - v;
}

// ---------------- scan3 + branch-params (last block) ----------------
__global__ void k_scan3b(int* offs, const int* __restrict__ bsums, int n,
                         const float4* __restrict__ partial4,
                         const float* __restrict__ Wd, const float* __restrict__ bndg,
                         const float* __restrict__ Wg, const float* __restrict__ bngg,
                         float* ad, float* ag, float* mus, float fn) {
    if (blockIdx.x + 1 < gridDim.x) {
        int i = blockIdx.x * blockDim.x + threadIdx.x;
        if (i < n) offs[i] += bsums[blockIdx.x];
        return;
    }
    __shared__ float scal[4];
    int j = threadIdx.x;
    if (j < 4) {
        float acc = 0.0f;
        for (int b = 0; b < SSTAT_BLOCKS; ++b) acc += ((const float*)&partial4[b])[j];
        scal[j] = acc;
    }
    __syncthreads();
    if (j < 128) {
        float mu_d = scal[0] / fn, var_d = scal[1] / fn - mu_d * mu_d;
        float mu_g = scal[2] / fn, var_g = scal[3] / fn - mu_g * mu_g;
        var_d = fmaxf(var_d, 0.0f);
        var_g = fmaxf(var_g, 0.0f);
        ad[j] = Wd[j] * bndg[j] * rsqrtf(var_d * Wd[j] * Wd[j] + BN_EPS);
        ag[j] = Wg[j] * bngg[j] * rsqrtf(var_g * Wg[j] * Wg[j] + BN_EPS);
        if (j == 0) { mus[0] = mu_d; mus[1] = mu_g; }
    }
}

// ---------------- CSR fill (+ 2 sort blocks at the end) ----------------
__global__ void k_fill_sort(const int* __restrict__ src, const int* __restrict__ dst,
                            const float* __restrict__ ew, const unsigned short* __restrict__ rank,
                            const float* __restrict__ dinv, const int* __restrict__ offs,
                            const int* __restrict__ base,
                            int2* __restrict__ cpair, int e, int n, int nbE,
                            const float* __restrict__ ad, const float* __restrict__ bndb,
                            const float* __restrict__ ag, const float* __restrict__ bngb,
                            float* __restrict__ sortd, float* __restrict__ sortg) {
    if (blockIdx.x < (unsigned)nbE) {
        int i = blockIdx.x * 256 + threadIdx.x;
        if (i < e) {
            int rep = (i >> 8) & (NREP - 1);
            int s = src[i], d = dst[i];
            float c = dinv[s] * ew[i] * dinv[d];
            int p = offs[d] + base[(size_t)rep * n + d] + (int)rank[i];
            int2 pr;
            pr.x = s;
            pr.y = __float_as_int(c);
            cpair[p] = pr;
        }
        return;
    }
    int which = blockIdx.x - nbE;   // 0 = dist, 1 = degree
    const float* a = which ? ag : ad;
    const float* b = which ? bngb : bndb;
    float* sorted = which ? sortg : sortd;
    __shared__ float t[128];
    int j = threadIdx.x;
    if (j < 128) {
        float aj = a[j], bj = b[j];
        float tj;
        if (aj != 0.0f) tj = -bj / aj;
        else tj = (bj > 0.0f) ? -1e30f : 1e30f;
        t[j] = tj;
    }
    __syncthreads();
    if (j < 128) {
        float tj = t[j];
        int rank_ = 0;
        for (int k = 0; k < 128; k++) {
            float tk = t[k];
            if (tk < tj || (tk == tj && k < j)) rank_++;
        }
        sorted[rank_] = tj;
    }
}

// ---------------- column-partial reduce + BN params (last-block ticket) ----------------
__global__ void k_colbn(const float* __restrict__ partial, float* stats, int* ctr,
                        const float* __restrict__ g, const float* __restrict__ b,
                        float* scale, float* shift, float n) {
    int tid = threadIdx.x;
    const int rows = AGG_BLOCKS / COLRED_BLOCKS;
    float acc = 0.0f;
    for (int j = blockIdx.x * rows; j < (blockIdx.x + 1) * rows; ++j)
        acc += partial[j * 256 + tid];
    atomicAdd(&stats[tid], acc);
    __threadfence();
    __syncthreads();
    __shared__ int lastf;
    if (tid == 0) lastf = (atomicAdd(ctr, 1) == COLRED_BLOCKS - 1) ? 1 : 0;
    __syncthreads();
    if (lastf && tid < 128) {
        // atomic reads: coherent across XCDs (plain loads could see stale L2)
        float sum = atomicAdd(&stats[tid], 0.0f);
        float sq  = atomicAdd(&stats[128 + tid], 0.0f);
        float mean = sum / n;
        float var = fmaxf(sq / n - mean * mean, 0.0f);
        float sc = g[tid] * rsqrtf(var + BN_EPS);
        scale[tid] = sc;
        shift[tid] = b[tid] - mean * sc;
    }
}

// ---------------- aggregation (bf16 gather) + fused BN col-stats + extra roles ----------------
// OUTMODE 0: write fp32 float2;  OUTMODE 1: write packed bf16
// Blocks >= AGG_BLOCKS run PWL-table / PWL-index roles (agg1 launch only).
template <int OUTMODE>
__global__ __launch_bounds__(256) void k_aggregate(
    const unsigned short* __restrict__ h, const float* __restrict__ dinv,
    const int* __restrict__ offs, const int* __restrict__ counts,
    const int2* __restrict__ cpair, void* __restrict__ out,
    float* __restrict__ partial, int n,
    const float* __restrict__ ad, const float* __restrict__ bndb,
    const float* __restrict__ agv, const float* __restrict__ bngb,
    const float* __restrict__ Wm, const float* __restrict__ sortd,
    const float* __restrict__ sortg, float* __restrict__ tabd, float* __restrict__ tabg,
    const float* __restrict__ mus, const float* __restrict__ dist,
    const float* __restrict__ degf,
    int* __restrict__ pdx, int* __restrict__ pgx,
    float* __restrict__ vdc, float* __restrict__ vgc) {
    if (blockIdx.x >= AGG_BLOCKS) {
        int xb = blockIdx.x - AGG_BLOCKS;
        if (xb < 258) {
            // PWL-table role
            int which = xb >= 129;
            int p = xb - which * 129;
            int c = threadIdx.x;
            if (c >= 128) return;
            const float* a = which ? agv : ad;
            const float* b = which ? bngb : bndb;
            const float* sorted = which ? sortg : sortd;
            const float* Wm2 = Wm + (which ? 256 : 128) * 128;
            float* tab = which ? tabg : tabd;
            float lo = (p == 0) ? -1e30f : sorted[p - 1];
            float hi = (p == 128) ? 1e30f : sorted[p];
            float vm = 0.5f * lo + 0.5f * hi;
            float As = 0.0f, Bs = 0.0f;
            for (int j = 0; j < 128; j++) {
                float aj = a[j], bj = b[j];
                if (fmaf(aj, vm, bj) > 0.0f) {
                    float w = Wm2[j * 128 + c];
                    As = fmaf(aj, w, As);
                    Bs = fmaf(bj, w, Bs);
                }
            }
            tab[p * 256 + c] = As;
            tab[p * 256 + 128 + c] = Bs;
        } else {
            // PWL-index role (grid-stride over nodes)
            __shared__ float sdg[2][128];
            if (threadIdx.x < 128) {
                sdg[0][threadIdx.x] = sortd[threadIdx.x];
                sdg[1][threadIdx.x] = sortg[threadIdx.x];
            }
            __syncthreads();
            int nb = gridDim.x - AGG_BLOCKS - 258;
            float m0 = mus[0], m1 = mus[1];
            for (int i = (xb - 258) * 256 + threadIdx.x; i < n; i += nb * 256) {
                float vd = dist[i] - m0, vg = degf[i] - m1;
                int lo = 0, hi = 128;
                while (lo < hi) { int m = (lo + hi) >> 1; if (sdg[0][m] < vd) lo = m + 1; else hi = m; }
                pdx[i] = lo; vdc[i] = vd;
                lo = 0; hi = 128;
                while (lo < hi) { int m = (lo + hi) >> 1; if (sdg[1][m] < vg) lo = m + 1; else hi = m; }
                pgx[i] = lo; vgc[i] = vg;
            }
        }
        return;
    }

    int lane = threadIdx.x & 63;
    int wv = __builtin_amdgcn_readfirstlane(threadIdx.x >> 6);
    int gw = blockIdx.x * 4 + wv;
    int nw = AGG_BLOCKS * 4;
    const unsigned int* hp = (const unsigned int*)h;

    float s0 = 0, q0 = 0, s1 = 0, q1 = 0;

    int wid = gw;
    unsigned int us = 0; float di = 0.f; int p = 0, cnt = 0;
    if (wid < n) {
        us = hp[(size_t)wid * 64 + lane];
        di = dinv[wid];
        p = __builtin_amdgcn_readfirstlane(offs[wid]);
        cnt = __builtin_amdgcn_readfirstlane(counts[wid]);
    }
    while (wid < n) {
        int nxt = wid + nw;
        unsigned int us_n = 0; float di_n = 0.f; int p_n = 0, cnt_n = 0;
        if (nxt < n) {
            us_n = hp[(size_t)nxt * 64 + lane];
            di_n = dinv[nxt];
            p_n = __builtin_amdgcn_readfirstlane(offs[nxt]);
            cnt_n = __builtin_amdgcn_readfirstlane(counts[nxt]);
        }

        float d2 = di * di;
        float ax = d2 * lo16f(us), ay = d2 * hi16f(us);
        int k = 0;
        for (; k + 8 <= cnt; k += 8) {
            int4 ea = *(const int4*)&cpair[p + k];
            int4 eb = *(const int4*)&cpair[p + k + 2];
            int4 ec = *(const int4*)&cpair[p + k + 4];
            int4 ed = *(const int4*)&cpair[p + k + 6];
            unsigned int u0 = hp[(size_t)ea.x * 64 + lane];
            unsigned int u1 = hp[(size_t)ea.z * 64 + lane];
            unsigned int u2 = hp[(size_t)eb.x * 64 + lane];
            unsigned int u3 = hp[(size_t)eb.z * 64 + lane];
            unsigned int u4 = hp[(size_t)ec.x * 64 + lane];
            unsigned int u5 = hp[(size_t)ec.z * 64 + lane];
            unsigned int u6 = hp[(size_t)ed.x * 64 + lane];
            unsigned int u7 = hp[(size_t)ed.z * 64 + lane];
            float c0 = __int_as_float(ea.y), c1 = __int_as_float(ea.w);
            float c2 = __int_as_float(eb.y), c3 = __int_as_float(eb.w);
            float c4 = __int_as_float(ec.y), c5 = __int_as_float(ec.w);
            float c6 = __int_as_float(ed.y), c7 = __int_as_float(ed.w);
            ax = fmaf(c0, lo16f(u0), ax); ay = fmaf(c0, hi16f(u0), ay);
            ax = fmaf(c1, lo16f(u1), ax); ay = fmaf(c1, hi16f(u1), ay);
            ax = fmaf(c2, lo16f(u2), ax); ay = fmaf(c2, hi16f(u2), ay);
            ax = fmaf(c3, lo16f(u3), ax); ay = fmaf(c3, hi16f(u3), ay);
            ax = fmaf(c4, lo16f(u4), ax); ay = fmaf(c4, hi16f(u4), ay);
            ax = fmaf(c5, lo16f(u5), ax); ay = fmaf(c5, hi16f(u5), ay);
            ax = fmaf(c6, lo16f(u6), ax); ay = fmaf(c6, hi16f(u6), ay);
            ax = fmaf(c7, lo16f(u7), ax); ay = fmaf(c7, hi16f(u7), ay);
        }
        if (k + 4 <= cnt) {
            int4 ea = *(const int4*)&cpair[p + k];
            int4 eb = *(const int4*)&cpair[p + k + 2];
            unsigned int u0 = hp[(size_t)ea.x * 64 + lane];
            unsigned int u1 = hp[(size_t)ea.z * 64 + lane];
            unsigned int u2 = hp[(size_t)eb.x * 64 + lane];
            unsigned int u3 = hp[(size_t)eb.z * 64 + lane];
            float c0 = __int_as_float(ea.y), c1 = __int_as_float(ea.w);
            float c2 = __int_as_float(eb.y), c3 = __int_as_float(eb.w);
            ax = fmaf(c0, lo16f(u0), ax); ay = fmaf(c0, hi16f(u0), ay);
            ax = fmaf(c1, lo16f(u1), ax); ay = fmaf(c1, hi16f(u1), ay);
            ax = fmaf(c2, lo16f(u2), ax); ay = fmaf(c2, hi16f(u2), ay);
            ax = fmaf(c3, lo16f(u3), ax); ay = fmaf(c3, hi16f(u3), ay);
            k += 4;
        }
        if (k + 2 <= cnt) {
            int4 ee = *(const int4*)&cpair[p + k];
            unsigned int u0 = hp[(size_t)ee.x * 64 + lane];
            unsigned int u1 = hp[(size_t)ee.z * 64 + lane];
            float c0 = __int_as_float(ee.y), c1 = __int_as_float(ee.w);
            ax = fmaf(c0, lo16f(u0), ax); ay = fmaf(c0, hi16f(u0), ay);
            ax = fmaf(c1, lo16f(u1), ax); ay = fmaf(c1, hi16f(u1), ay);
            k += 2;
        }
        if (k < cnt) {
            int2 e0 = cpair[p + k];
            unsigned int u0 = hp[(size_t)e0.x * 64 + lane];
            float c0 = __int_as_float(e0.y);
            ax = fmaf(c0, lo16f(u0), ax); ay = fmaf(c0, hi16f(u0), ay);
        }
        if (OUTMODE == 0) {
            float2 o; o.x = ax; o.y = ay;
            ((float2*)out)[(size_t)wid * 64 + lane] = o;
        } else {
            unsigned int u = (unsigned int)(unsigned short)f2bf(ax) |
                             ((unsigned int)(unsigned short)f2bf(ay) << 16);
            ((unsigned int*)out)[(size_t)wid * 64 + lane] = u;
        }
        s0 += ax; q0 = fmaf(ax, ax, q0);
        s1 += ay; q1 = fmaf(ay, ay, q1);

        wid = nxt;
        us = us_n; di = di_n; p = p_n; cnt = cnt_n;
    }

    __shared__ float red[4][256];
    red[0][threadIdx.x] = s0; red[1][threadIdx.x] = q0;
    red[2][threadIdx.x] = s1; red[3][threadIdx.x] = q1;
    __syncthreads();
    if (wv == 0) {
        float a = 0, b = 0, c = 0, d = 0;
#pragma unroll
        for (int w = 0; w < 4; ++w) {
            a += red[0][w * 64 + lane];
            b += red[1][w * 64 + lane];
            c += red[2][w * 64 + lane];
            d += red[3][w * 64 + lane];
        }
        float* pr = partial + (size_t)blockIdx.x * 256;
        pr[2 * lane]       = a;
        pr[2 * lane + 1]   = c;
        pr[128 + 2 * lane]     = b;
        pr[128 + 2 * lane + 1] = d;
    }
}

extern "C" void kernel_launch(void* const* d_in, const int* in_sizes, int n_in,
                              void* d_out, int out_size, void* d_ws, size_t ws_size,
                              hipStream_t stream) {
    const float* x    = (const float*)d_in[0];
    const int*   eidx = (const int*)d_in[1];
    const float* ew   = (const float*)d_in[2];
    const float* dist = (const float*)d_in[3];
    const float* degf = (const float*)d_in[4];
    const float* W1   = (const float*)d_in[5];
    const float* W2   = (const float*)d_in[7];
    const float* bn1g = (const float*)d_in[9];
    const float* bn1b = (const float*)d_in[10];
    const float* bn2g = (const float*)d_in[11];
    const float* bn2b = (const float*)d_in[12];
    const float* Wd   = (const float*)d_in[13];
    const float* bndg = (const float*)d_in[15];
    const float* bndb = (const float*)d_in[16];
    const float* Wg   = (const float*)d_in[17];
    const float* bngg = (const float*)d_in[19];
    const float* bngb = (const float*)d_in[20];
    const float* Wm   = (const float*)d_in[21];
    const float* bm   = (const float*)d_in[22];

    const int n = in_sizes[0] / 128;
    const int e = in_sizes[2];
    const int total = n * 128;
    const int* esrc = eidx;
    const int* edst = eidx + e;

    auto align256 = [](size_t v) { return (v + 255) & ~(size_t)255; };
    char* ws = (char*)d_ws;
    size_t off = 0;
    unsigned short* planeB = (unsigned short*)(ws + off); off += align256((size_t)total * 2);
    unsigned short* planeC = (unsigned short*)(ws + off); off += align256((size_t)total * 2);
    float* aggout = (float*)(ws + off); off += align256((size_t)total * 4);
    int2*  cpair  = (int2*)(ws + off);  off += align256((size_t)e * 8);
    float* partial= (float*)(ws + off); off += align256((size_t)AGG_BLOCKS * 256 * 4);
    float* dinv   = (float*)(ws + off); off += align256((size_t)n * 4);
    int*   counts = (int*)(ws + off);   off += align256((size_t)n * 4);
    int*   offs   = (int*)(ws + off);   off += align256((size_t)n * 4);
    int*   pdx    = (int*)(ws + off);   off += align256((size_t)n * 4);
    int*   pgx    = (int*)(ws + off);   off += align256((size_t)n * 4);
    float* vdc    = (float*)(ws + off); off += align256((size_t)n * 4);
    float* vgc    = (float*)(ws + off); off += align256((size_t)n * 4);
    int*   bsums  = (int*)(ws + off);   off += 4096;
    float* stats  = (float*)(ws + off); off += 4096;
    float* params = (float*)(ws + off); off += 4096;
    float* sortd  = (float*)(ws + off); off += 1024;
    float* sortg  = (float*)(ws + off); off += 1024;
    float4* part4 = (float4*)(ws + off); off += align256((size_t)SSTAT_BLOCKS * 16);
    float* tabd   = (float*)(ws + off); off += align256((size_t)129 * 256 * 4);
    float* tabg   = (float*)(ws + off); off += align256((size_t)129 * 256 * 4);

    // aliases into regions dead until k_aggregate<0> writes aggout:
    unsigned long long* pack64 = (unsigned long long*)aggout;            // NREP*n u64
    int* base = (int*)(aggout + (size_t)NREP * n * 2 + 256);             // NREP*n int
    unsigned short* rank = (unsigned short*)planeC;                      // dead before agg1 output

    float* s1     = stats;
    float* s2     = stats + 256;
    int*   ctr1   = (int*)(stats + 512);   // zeroed by the stats memset each call
    int*   ctr2   = (int*)(stats + 513);
    float* scale1 = params;
    float* shift1 = params + 128;
    float* scale2 = params + 256;
    float* shift2 = params + 384;
    float* ad     = params + 512;
    float* ag     = params + 640;
    float* mus    = params + 768;

    const int nbN = (n + 255) / 256;
    const int nbE = (e + 255) / 256;

    // zero the atomic histograms + BN stat accumulators + ticket counters
    hipMemsetAsync(pack64, 0, (size_t)NREP * n * 8, stream);
    hipMemsetAsync(stats, 0, 4096, stream);

    // MEGA1: gemm1 (x@W1 -> planeB bf16) || edge_prep atomics || scalar stats
    k_mega1<<<GEMM_BLOCKS + nbE + SSTAT_BLOCKS, 256, 0, stream>>>(
        edst, ew, pack64, rank, e, n, x, W1, planeB, dist, degf, part4, nbE);

    // scan + branch params
    k_scan1<<<nbN, 256, 0, stream>>>(pack64, counts, offs, bsums, dinv, base, n);
    k_scan2<<<1, 512, 0, stream>>>(bsums, nbN);
    k_scan3b<<<nbN + 1, 256, 0, stream>>>(offs, bsums, n, part4, Wd, bndg, Wg, bngg,
                                          ad, ag, mus, (float)n);

    // CSR fill (+ PWL breakpoint sorts)
    k_fill_sort<<<nbE + 2, 256, 0, stream>>>(esrc, edst, ew, rank, dinv, offs, base,
                                             cpair, e, n, nbE, ad, bndb, ag, bngb,
                                             sortd, sortg);

    // layer 1 aggregation (+ hidden PWL-table & PWL-index roles), then fused colred+BN
    k_aggregate<1><<<AGG_BLOCKS + 258 + 256, 256, 0, stream>>>(
        planeB, dinv, offs, counts, cpair, planeC, partial, n,
        ad, bndb, ag, bngb, Wm, sortd, sortg, tabd, tabg,
        mus, dist, degf, pdx, pgx, vdc, vgc);
    k_colbn<<<COLRED_BLOCKS, 256, 0, stream>>>(partial, s1, ctr1, bn1g, bn1b,
                                               scale1, shift1, (float)n);

    // layer 2: h2 = agg(relu(bn1(h1)) @ W2)
    gemm_mfma<1><<<1024, 256, 0, stream>>>(planeC, W2, planeB, scale1, shift1, nullptr,
                                           nullptr, nullptr, nullptr, nullptr,
                                           nullptr, nullptr, n);
    k_aggregate<0><<<AGG_BLOCKS, 256, 0, stream>>>(
        planeB, dinv, offs, counts, cpair, aggout, partial, n,
        nullptr, nullptr, nullptr, nullptr, nullptr, nullptr, nullptr, nullptr, nullptr,
        nullptr, nullptr, nullptr, nullptr, nullptr, nullptr, nullptr);
    k_colbn<<<COLRED_BLOCKS, 256, 0, stream>>>(partial, s2, ctr2, bn2g, bn2b,
                                               scale2, shift2, (float)n);

    // final: out = relu(bn2(h2)) @ Wm[0:128] + bm + PWL_d + PWL_g (pipelined)
    gemm_mfma<2><<<1024, 256, 0, stream>>>(aggout, Wm, d_out, scale2, shift2, bm,
                                           pdx, pgx, vdc, vgc, tabd, tabg, n);
}

// Round 10
// 425.742 us; speedup vs baseline: 1.0581x; 1.0581x over previous
//
#include <hip/hip_runtime.h>

#define BN_EPS 1e-5f
#define AGG_BLOCKS 2048
#define COLRED_BLOCKS 64   // AGG_BLOCKS / COLRED_BLOCKS rows each
#define SSTAT_BLOCKS 64
#define NREP 8             // histogram replicas for edge_prep atomics
#define GEMM_BLOCKS 1024

typedef __attribute__((ext_vector_type(8))) short short8;
typedef __attribute__((ext_vector_type(4))) float f32x4;

#define MFMA16(a, b, c) __builtin_amdgcn_mfma_f32_16x16x32_bf16(a, b, c, 0, 0, 0)

__device__ __forceinline__ short f2bf(float f) {
    unsigned int u = __float_as_uint(f);
    u = (u + 0x7FFFu + ((u >> 16) & 1u)) >> 16;
    return (short)u;
}
__device__ __forceinline__ float bf2f(short s) {
    return __uint_as_float(((unsigned int)(unsigned short)s) << 16);
}
__device__ __forceinline__ float lo16f(unsigned int u) { return __uint_as_float(u << 16); }
__device__ __forceinline__ float hi16f(unsigned int u) { return __uint_as_float(u & 0xffff0000u); }

// ================= GEMM device body (register-resident W, MFMA) =================
// ASRC 0: A = fp32 raw (x)                      -> C bf16 plane   (2-deep pipeline)
// ASRC 1: A = bf16 raw + BN+ReLU in-register    -> C bf16 plane   (2-deep pipeline)
// ASRC 2: A = fp32 + BN+ReLU + hi/lo split; 3-pass MFMA; bias+PWL epilogue -> C fp32
//         (NO prefetch pipeline: doubling live A-frags costs ~64 VGPR -> occupancy drop,
//          measured regression in round 9. Latency hidden via grid-size TLP instead.)
template <int ASRC>
__device__ __forceinline__ void gemm_body(
    const void* __restrict__ Ain, const float* __restrict__ W, void* __restrict__ Cout,
    const float* __restrict__ scale, const float* __restrict__ shift,
    const float* __restrict__ bias,
    const int* __restrict__ pdx, const int* __restrict__ pgx,
    const float* __restrict__ vdc, const float* __restrict__ vgc,
    const float* __restrict__ tabd, const float* __restrict__ tabg,
    int n, int bid, int nb) {
    constexpr bool FINAL = (ASRC == 2);
    const int lane = threadIdx.x & 63;
    const int wave = threadIdx.x >> 6;
    const int l15 = lane & 15, lg = lane >> 4;
    const int cbase = wave * 32;

    short8 wh[4][2], wl[4][2];
#pragma unroll
    for (int kt = 0; kt < 4; ++kt) {
#pragma unroll
        for (int cf = 0; cf < 2; ++cf) {
            int col = cbase + 16 * cf + l15;
            short8 hh, ll;
#pragma unroll
            for (int e = 0; e < 8; ++e) {
                float wv = W[(32 * kt + 8 * lg + e) * 128 + col];
                short hs = f2bf(wv);
                hh[e] = hs;
                if (FINAL) ll[e] = f2bf(wv - bf2f(hs));
            }
            wh[kt][cf] = hh;
            if (FINAL) wl[kt][cf] = ll;
        }
    }

    float4 scr[4][2], shr[4][2];
    if (ASRC == 1) {
#pragma unroll
        for (int kt = 0; kt < 4; ++kt) {
            scr[kt][0] = *(const float4*)&scale[32 * kt + 8 * lg];
            scr[kt][1] = *(const float4*)&scale[32 * kt + 8 * lg + 4];
            shr[kt][0] = *(const float4*)&shift[32 * kt + 8 * lg];
            shr[kt][1] = *(const float4*)&shift[32 * kt + 8 * lg + 4];
        }
    }

    float b0 = 0.f, b1 = 0.f;
    if (FINAL) { b0 = bias[cbase + l15]; b1 = bias[cbase + 16 + l15]; }

    const int ntiles = (n + 15) >> 4;

    short8 ah[4], al[4], nh[4];
    auto loada = [&](int t, short8* H, short8* L) {
        int row = t * 16 + l15;
        if (row >= n) row = n - 1;
        if (ASRC == 0) {
            const float* p = (const float*)Ain + (size_t)row * 128 + 8 * lg;
#pragma unroll
            for (int kt = 0; kt < 4; ++kt) {
                float4 u = *(const float4*)(p + 32 * kt);
                float4 v = *(const float4*)(p + 32 * kt + 4);
                short8 h;
                h[0] = f2bf(u.x); h[1] = f2bf(u.y); h[2] = f2bf(u.z); h[3] = f2bf(u.w);
                h[4] = f2bf(v.x); h[5] = f2bf(v.y); h[6] = f2bf(v.z); h[7] = f2bf(v.w);
                H[kt] = h;
            }
        } else if (ASRC == 1) {
            const unsigned short* p = (const unsigned short*)Ain + (size_t)row * 128 + 8 * lg;
#pragma unroll
            for (int kt = 0; kt < 4; ++kt) {
                short8 s = *(const short8*)(p + 32 * kt);
                short8 h;
#pragma unroll
                for (int e = 0; e < 8; ++e) {
                    float sc = (e < 4) ? ((const float*)&scr[kt][0])[e] : ((const float*)&scr[kt][1])[e - 4];
                    float sh = (e < 4) ? ((const float*)&shr[kt][0])[e] : ((const float*)&shr[kt][1])[e - 4];
                    float f = fmaxf(0.0f, fmaf(bf2f(s[e]), sc, sh));
                    h[e] = f2bf(f);
                }
                H[kt] = h;
            }
        } else {
            const float* p = (const float*)Ain + (size_t)row * 128 + 8 * lg;
#pragma unroll
            for (int kt = 0; kt < 4; ++kt) {
                float4 u = *(const float4*)(p + 32 * kt);
                float4 v = *(const float4*)(p + 32 * kt + 4);
                float4 sa = *(const float4*)&scale[32 * kt + 8 * lg];
                float4 sb = *(const float4*)&scale[32 * kt + 8 * lg + 4];
                float4 ta = *(const float4*)&shift[32 * kt + 8 * lg];
                float4 tb = *(const float4*)&shift[32 * kt + 8 * lg + 4];
                float f[8];
                f[0] = fmaxf(0.f, fmaf(u.x, sa.x, ta.x));
                f[1] = fmaxf(0.f, fmaf(u.y, sa.y, ta.y));
                f[2] = fmaxf(0.f, fmaf(u.z, sa.z, ta.z));
                f[3] = fmaxf(0.f, fmaf(u.w, sa.w, ta.w));
                f[4] = fmaxf(0.f, fmaf(v.x, sb.x, tb.x));
                f[5] = fmaxf(0.f, fmaf(v.y, sb.y, tb.y));
                f[6] = fmaxf(0.f, fmaf(v.z, sb.z, tb.z));
                f[7] = fmaxf(0.f, fmaf(v.w, sb.w, tb.w));
                short8 h, l;
#pragma unroll
                for (int e = 0; e < 8; ++e) {
                    short hs = f2bf(f[e]);
                    h[e] = hs;
                    l[e] = f2bf(f[e] - bf2f(hs));
                }
                H[kt] = h;
                L[kt] = l;
            }
        }
    };

    int tile = bid;
    if (!FINAL && tile < ntiles) loada(tile, ah, nullptr);
    for (; tile < ntiles; tile += nb) {
        if (!FINAL) {
            int nx = tile + nb;
            if (nx < ntiles) loada(nx, nh, nullptr);   // 2-deep pipeline
        } else {
            loada(tile, ah, al);
        }

        f32x4 acc0 = {0.f, 0.f, 0.f, 0.f};
        f32x4 acc1 = {0.f, 0.f, 0.f, 0.f};
#pragma unroll
        for (int kt = 0; kt < 4; ++kt) {
            acc0 = MFMA16(ah[kt], wh[kt][0], acc0);
            acc1 = MFMA16(ah[kt], wh[kt][1], acc1);
        }
        if (FINAL) {
#pragma unroll
            for (int kt = 0; kt < 4; ++kt) {
                acc0 = MFMA16(al[kt], wh[kt][0], acc0);
                acc1 = MFMA16(al[kt], wh[kt][1], acc1);
            }
#pragma unroll
            for (int kt = 0; kt < 4; ++kt) {
                acc0 = MFMA16(ah[kt], wl[kt][0], acc0);
                acc1 = MFMA16(ah[kt], wl[kt][1], acc1);
            }
        }

        int rbase = tile * 16;
        if constexpr (!FINAL) {
            unsigned short* C = (unsigned short*)Cout;
#pragma unroll
            for (int r = 0; r < 4; ++r) {
                int row = rbase + lg * 4 + r;
                if (row < n) {
                    C[(size_t)row * 128 + cbase + l15]      = (unsigned short)f2bf(acc0[r]);
                    C[(size_t)row * 128 + cbase + 16 + l15] = (unsigned short)f2bf(acc1[r]);
                }
            }
        } else {
            float* C = (float*)Cout;
#pragma unroll
            for (int r = 0; r < 4; ++r) {
                int row = rbase + lg * 4 + r;
                int rc = row < n ? row : n - 1;
                float vd = vdc[rc], vg = vgc[rc];
                int pd = pdx[rc] * 256, pg = pgx[rc] * 256;
                int c0 = cbase + l15, c1 = cbase + 16 + l15;
                float v0 = acc0[r] + b0, v1 = acc1[r] + b1;
                v0 = fmaf(tabd[pd + c0], vd, v0) + tabd[pd + 128 + c0];
                v1 = fmaf(tabd[pd + c1], vd, v1) + tabd[pd + 128 + c1];
                v0 = fmaf(tabg[pg + c0], vg, v0) + tabg[pg + 128 + c0];
                v1 = fmaf(tabg[pg + c1], vg, v1) + tabg[pg + 128 + c1];
                if (row < n) {
                    C[(size_t)row * 128 + c0] = v0;
                    C[(size_t)row * 128 + c1] = v1;
                }
            }
        }
        if (!FINAL) {
#pragma unroll
            for (int kt = 0; kt < 4; ++kt) ah[kt] = nh[kt];
        }
    }
}

template <int ASRC>
__global__ __launch_bounds__(256) void gemm_mfma(
    const void* __restrict__ Ain, const float* __restrict__ W, void* __restrict__ Cout,
    const float* __restrict__ scale, const float* __restrict__ shift,
    const float* __restrict__ bias,
    const int* __restrict__ pdx, const int* __restrict__ pgx,
    const float* __restrict__ vdc, const float* __restrict__ vgc,
    const float* __restrict__ tabd, const float* __restrict__ tabg, int n) {
    gemm_body<ASRC>(Ain, W, Cout, scale, shift, bias, pdx, pgx, vdc, vgc, tabd, tabg,
                    n, blockIdx.x, gridDim.x);
}

// ================= MEGA1: gemm1 (blocks 0..GB) + edge_prep + scalar_stats =================
__global__ __launch_bounds__(256) void k_mega1(
    const int* __restrict__ dst, const float* __restrict__ ew,
    unsigned long long* __restrict__ pack64, unsigned short* __restrict__ rank,
    int e, int n,
    const float* __restrict__ x, const float* __restrict__ W1, void* __restrict__ planeB,
    const float* __restrict__ df, const float* __restrict__ gf,
    float4* __restrict__ partial4, int nbE) {
    if (blockIdx.x < GEMM_BLOCKS) {
        gemm_body<0>(x, W1, planeB, nullptr, nullptr, nullptr,
                     nullptr, nullptr, nullptr, nullptr, nullptr, nullptr,
                     n, blockIdx.x, GEMM_BLOCKS);
        return;
    }
    int bid = blockIdx.x - GEMM_BLOCKS;
    if (bid < nbE) {
        int i = bid * 256 + threadIdx.x;
        if (i < e) {
            int rep = bid & (NREP - 1);
            int d = dst[i];
            unsigned long long fx = (unsigned long long)(ew[i] * 1.099511627776e12f);  // 2^40
            unsigned long long old = atomicAdd(&pack64[(size_t)rep * n + d], (1ull << 54) | fx);
            rank[i] = (unsigned short)(old >> 54);
        }
        return;
    }
    // scalar-stats role
    int sb = bid - nbE;
    float sd = 0, sd2 = 0, sg = 0, sg2 = 0;
    for (int i = sb * 256 + threadIdx.x; i < n; i += SSTAT_BLOCKS * 256) {
        float a = df[i], b = gf[i];
        sd += a; sd2 += a * a; sg += b; sg2 += b * b;
    }
    for (int off = 32; off > 0; off >>= 1) {
        sd  += __shfl_down(sd, off, 64);
        sd2 += __shfl_down(sd2, off, 64);
        sg  += __shfl_down(sg, off, 64);
        sg2 += __shfl_down(sg2, off, 64);
    }
    __shared__ float4 wred[4];
    int lane = threadIdx.x & 63, wave = threadIdx.x >> 6;
    if (lane == 0) { float4 v; v.x = sd; v.y = sd2; v.z = sg; v.w = sg2; wred[wave] = v; }
    __syncthreads();
    if (threadIdx.x == 0) {
        float4 a = wred[0], b = wred[1], c = wred[2], d = wred[3];
        float4 o;
        o.x = a.x + b.x + c.x + d.x;
        o.y = a.y + b.y + c.y + d.y;
        o.z = a.z + b.z + c.z + d.z;
        o.w = a.w + b.w + c.w + d.w;
        partial4[sb] = o;
    }
}

// ---------------- scan: combine replicas -> counts/dinv/base, block-scan offs ----------------
__global__ void k_scan1(const unsigned long long* __restrict__ pack64,
                        int* counts, int* offs, int* bsums, float* dinv,
                        int* __restrict__ base, int n) {
    __shared__ int tmp[256];
    int t = threadIdx.x;
    int i = blockIdx.x * 256 + t;
    int v = 0;
    if (i < n) {
        unsigned long long degsum = 0;
        int c = 0;
#pragma unroll
        for (int r = 0; r < NREP; ++r) {
            unsigned long long p = pack64[(size_t)r * n + i];
            base[(size_t)r * n + i] = c;
            c += (int)(p >> 54);
            degsum += (p & ((1ull << 54) - 1ull));
        }
        float deg = 1.0f + (float)degsum * 9.094947017729282e-13f; // 2^-40
        dinv[i] = rsqrtf(deg);
        counts[i] = c;
        v = c;
    }
    tmp[t] = v;
    __syncthreads();
    for (int d = 1; d < 256; d <<= 1) {
        int add = (t >= d) ? tmp[t - d] : 0;
        __syncthreads();
        tmp[t] += add;
        __syncthreads();
    }
    if (i < n) offs[i] = tmp[t] - v;
    if (t == 255) bsums[blockIdx.x] = tmp[255];
}

__global__ void k_scan2(int* bsums, int nb) {
    __shared__ int tmp[512];
    int t = threadIdx.x;
    int v = (t < nb) ? bsums[t] : 0;
    tmp[t] = v;
    __syncthreads();
    for (int d = 1; d < 512; d <<= 1) {
        int add = (t >= d) ? tmp[t - d] : 0;
        __syncthreads();
        tmp[t] += add;
        __syncthreads();
    }
    if (t < nb) bsums[t] = tmp[t] - v;
}

// ---------------- scan3 + branch-params (last block) ----------------
__global__ void k_scan3b(int* offs, const int* __restrict__ bsums, int n,
                         const float4* __restrict__ partial4,
                         const float* __restrict__ Wd, const float* __restrict__ bndg,
                         const float* __restrict__ Wg, const float* __restrict__ bngg,
                         float* ad, float* ag, float* mus, float fn) {
    if (blockIdx.x + 1 < gridDim.x) {
        int i = blockIdx.x * blockDim.x + threadIdx.x;
        if (i < n) offs[i] += bsums[blockIdx.x];
        return;
    }
    __shared__ float scal[4];
    int j = threadIdx.x;
    if (j < 4) {
        float acc = 0.0f;
        for (int b = 0; b < SSTAT_BLOCKS; ++b) acc += ((const float*)&partial4[b])[j];
        scal[j] = acc;
    }
    __syncthreads();
    if (j < 128) {
        float mu_d = scal[0] / fn, var_d = scal[1] / fn - mu_d * mu_d;
        float mu_g = scal[2] / fn, var_g = scal[3] / fn - mu_g * mu_g;
        var_d = fmaxf(var_d, 0.0f);
        var_g = fmaxf(var_g, 0.0f);
        ad[j] = Wd[j] * bndg[j] * rsqrtf(var_d * Wd[j] * Wd[j] + BN_EPS);
        ag[j] = Wg[j] * bngg[j] * rsqrtf(var_g * Wg[j] * Wg[j] + BN_EPS);
        if (j == 0) { mus[0] = mu_d; mus[1] = mu_g; }
    }
}

// ---------------- CSR fill (+ 2 sort blocks at the end) ----------------
__global__ void k_fill_sort(const int* __restrict__ src, const int* __restrict__ dst,
                            const float* __restrict__ ew, const unsigned short* __restrict__ rank,
                            const float* __restrict__ dinv, const int* __restrict__ offs,
                            const int* __restrict__ base,
                            int2* __restrict__ cpair, int e, int n, int nbE,
                            const float* __restrict__ ad, const float* __restrict__ bndb,
                            const float* __restrict__ ag, const float* __restrict__ bngb,
                            float* __restrict__ sortd, float* __restrict__ sortg) {
    if (blockIdx.x < (unsigned)nbE) {
        int i = blockIdx.x * 256 + threadIdx.x;
        if (i < e) {
            int rep = (i >> 8) & (NREP - 1);
            int s = src[i], d = dst[i];
            float c = dinv[s] * ew[i] * dinv[d];
            int p = offs[d] + base[(size_t)rep * n + d] + (int)rank[i];
            int2 pr;
            pr.x = s;
            pr.y = __float_as_int(c);
            cpair[p] = pr;
        }
        return;
    }
    int which = blockIdx.x - nbE;   // 0 = dist, 1 = degree
    const float* a = which ? ag : ad;
    const float* b = which ? bngb : bndb;
    float* sorted = which ? sortg : sortd;
    __shared__ float t[128];
    int j = threadIdx.x;
    if (j < 128) {
        float aj = a[j], bj = b[j];
        float tj;
        if (aj != 0.0f) tj = -bj / aj;
        else tj = (bj > 0.0f) ? -1e30f : 1e30f;
        t[j] = tj;
    }
    __syncthreads();
    if (j < 128) {
        float tj = t[j];
        int rank_ = 0;
        for (int k = 0; k < 128; k++) {
            float tk = t[k];
            if (tk < tj || (tk == tj && k < j)) rank_++;
        }
        sorted[rank_] = tj;
    }
}

// ---------------- PWL tables (blocks 0..257) + per-node interval index (rest) ----------------
__global__ __launch_bounds__(256) void k_tab_idx(
    const float* __restrict__ ad, const float* __restrict__ bndb,
    const float* __restrict__ ag, const float* __restrict__ bngb,
    const float* __restrict__ Wm, const float* __restrict__ sortd,
    const float* __restrict__ sortg, float* __restrict__ tabd, float* __restrict__ tabg,
    const float* __restrict__ mus, const float* __restrict__ dist,
    const float* __restrict__ degf,
    int* __restrict__ pdx, int* __restrict__ pgx,
    float* __restrict__ vdc, float* __restrict__ vgc, int n) {
    if (blockIdx.x < 258) {
        int which = blockIdx.x >= 129;
        int p = blockIdx.x - which * 129;
        int c = threadIdx.x;
        if (c >= 128) return;
        const float* a = which ? ag : ad;
        const float* b = which ? bngb : bndb;
        const float* sorted = which ? sortg : sortd;
        const float* Wm2 = Wm + (which ? 256 : 128) * 128;
        float* tab = which ? tabg : tabd;
        float lo = (p == 0) ? -1e30f : sorted[p - 1];
        float hi = (p == 128) ? 1e30f : sorted[p];
        float vm = 0.5f * lo + 0.5f * hi;
        float As = 0.0f, Bs = 0.0f;
        for (int j = 0; j < 128; j++) {
            float aj = a[j], bj = b[j];
            if (fmaf(aj, vm, bj) > 0.0f) {
                float w = Wm2[j * 128 + c];
                As = fmaf(aj, w, As);
                Bs = fmaf(bj, w, Bs);
            }
        }
        tab[p * 256 + c] = As;
        tab[p * 256 + 128 + c] = Bs;
        return;
    }
    // per-node interval index role (grid-stride)
    __shared__ float sd[128], sg[128];
    if (threadIdx.x < 128) {
        sd[threadIdx.x] = sortd[threadIdx.x];
        sg[threadIdx.x] = sortg[threadIdx.x];
    }
    __syncthreads();
    int nb = gridDim.x - 258;
    float m0 = mus[0], m1 = mus[1];
    for (int i = (blockIdx.x - 258) * 256 + threadIdx.x; i < n; i += nb * 256) {
        float vd = dist[i] - m0, vg = degf[i] - m1;
        int lo = 0, hi = 128;
        while (lo < hi) { int m = (lo + hi) >> 1; if (sd[m] < vd) lo = m + 1; else hi = m; }
        pdx[i] = lo; vdc[i] = vd;
        lo = 0; hi = 128;
        while (lo < hi) { int m = (lo + hi) >> 1; if (sg[m] < vg) lo = m + 1; else hi = m; }
        pgx[i] = lo; vgc[i] = vg;
    }
}

// ---------------- column-partial reduce -> stats (64 blocks) ----------------
__global__ void k_colred(const float* __restrict__ partial, float* stats) {
    int tid = threadIdx.x;
    int b = blockIdx.x;
    const int rows = AGG_BLOCKS / COLRED_BLOCKS;
    float acc = 0.0f;
    for (int j = b * rows; j < (b + 1) * rows; ++j) acc += partial[j * 256 + tid];
    atomicAdd(&stats[tid], acc);
}

// ---------------- BN scale/shift ----------------
__global__ void k_bn_params(const float* __restrict__ stats, const float* __restrict__ g,
                            const float* __restrict__ b, float* scale, float* shift, float n) {
    int j = threadIdx.x;
    float mean = stats[j] / n;
    float var = stats[128 + j] / n - mean * mean;
    var = fmaxf(var, 0.0f);
    float sc = g[j] * rsqrtf(var + BN_EPS);
    scale[j] = sc;
    shift[j] = b[j] - mean * sc;
}

// ---------------- aggregation (bf16 gather) + fused BN col-stats ----------------
// OUTMODE 0: write fp32 float2;  OUTMODE 1: write packed bf16
template <int OUTMODE>
__global__ __launch_bounds__(256) void k_aggregate(
    const unsigned short* __restrict__ h, const float* __restrict__ dinv,
    const int* __restrict__ offs, const int* __restrict__ counts,
    const int2* __restrict__ cpair, void* __restrict__ out,
    float* __restrict__ partial, int n) {
    int lane = threadIdx.x & 63;
    int wv = __builtin_amdgcn_readfirstlane(threadIdx.x >> 6);
    int gw = blockIdx.x * 4 + wv;
    int nw = gridDim.x * 4;
    const unsigned int* hp = (const unsigned int*)h;

    float s0 = 0, q0 = 0, s1 = 0, q1 = 0;

    int wid = gw;
    unsigned int us = 0; float di = 0.f; int p = 0, cnt = 0;
    if (wid < n) {
        us = hp[(size_t)wid * 64 + lane];
        di = dinv[wid];
        p = __builtin_amdgcn_readfirstlane(offs[wid]);
        cnt = __builtin_amdgcn_readfirstlane(counts[wid]);
    }
    while (wid < n) {
        int nxt = wid + nw;
        unsigned int us_n = 0; float di_n = 0.f; int p_n = 0, cnt_n = 0;
        if (nxt < n) {
            us_n = hp[(size_t)nxt * 64 + lane];
            di_n = dinv[nxt];
            p_n = __builtin_amdgcn_readfirstlane(offs[nxt]);
            cnt_n = __builtin_amdgcn_readfirstlane(counts[nxt]);
        }

        float d2 = di * di;
        float ax = d2 * lo16f(us), ay = d2 * hi16f(us);
        int k = 0;
        for (; k + 8 <= cnt; k += 8) {
            int4 ea = *(const int4*)&cpair[p + k];
            int4 eb = *(const int4*)&cpair[p + k + 2];
            int4 ec = *(const int4*)&cpair[p + k + 4];
            int4 ed = *(const int4*)&cpair[p + k + 6];
            unsigned int u0 = hp[(size_t)ea.x * 64 + lane];
            unsigned int u1 = hp[(size_t)ea.z * 64 + lane];
            unsigned int u2 = hp[(size_t)eb.x * 64 + lane];
            unsigned int u3 = hp[(size_t)eb.z * 64 + lane];
            unsigned int u4 = hp[(size_t)ec.x * 64 + lane];
            unsigned int u5 = hp[(size_t)ec.z * 64 + lane];
            unsigned int u6 = hp[(size_t)ed.x * 64 + lane];
            unsigned int u7 = hp[(size_t)ed.z * 64 + lane];
            float c0 = __int_as_float(ea.y), c1 = __int_as_float(ea.w);
            float c2 = __int_as_float(eb.y), c3 = __int_as_float(eb.w);
            float c4 = __int_as_float(ec.y), c5 = __int_as_float(ec.w);
            float c6 = __int_as_float(ed.y), c7 = __int_as_float(ed.w);
            ax = fmaf(c0, lo16f(u0), ax); ay = fmaf(c0, hi16f(u0), ay);
            ax = fmaf(c1, lo16f(u1), ax); ay = fmaf(c1, hi16f(u1), ay);
            ax = fmaf(c2, lo16f(u2), ax); ay = fmaf(c2, hi16f(u2), ay);
            ax = fmaf(c3, lo16f(u3), ax); ay = fmaf(c3, hi16f(u3), ay);
            ax = fmaf(c4, lo16f(u4), ax); ay = fmaf(c4, hi16f(u4), ay);
            ax = fmaf(c5, lo16f(u5), ax); ay = fmaf(c5, hi16f(u5), ay);
            ax = fmaf(c6, lo16f(u6), ax); ay = fmaf(c6, hi16f(u6), ay);
            ax = fmaf(c7, lo16f(u7), ax); ay = fmaf(c7, hi16f(u7), ay);
        }
        if (k + 4 <= cnt) {
            int4 ea = *(const int4*)&cpair[p + k];
            int4 eb = *(const int4*)&cpair[p + k + 2];
            unsigned int u0 = hp[(size_t)ea.x * 64 + lane];
            unsigned int u1 = hp[(size_t)ea.z * 64 + lane];
            unsigned int u2 = hp[(size_t)eb.x * 64 + lane];
            unsigned int u3 = hp[(size_t)eb.z * 64 + lane];
            float c0 = __int_as_float(ea.y), c1 = __int_as_float(ea.w);
            float c2 = __int_as_float(eb.y), c3 = __int_as_float(eb.w);
            ax = fmaf(c0, lo16f(u0), ax); ay = fmaf(c0, hi16f(u0), ay);
            ax = fmaf(c1, lo16f(u1), ax); ay = fmaf(c1, hi16f(u1), ay);
            ax = fmaf(c2, lo16f(u2), ax); ay = fmaf(c2, hi16f(u2), ay);
            ax = fmaf(c3, lo16f(u3), ax); ay = fmaf(c3, hi16f(u3), ay);
            k += 4;
        }
        if (k + 2 <= cnt) {
            int4 ee = *(const int4*)&cpair[p + k];
            unsigned int u0 = hp[(size_t)ee.x * 64 + lane];
            unsigned int u1 = hp[(size_t)ee.z * 64 + lane];
            float c0 = __int_as_float(ee.y), c1 = __int_as_float(ee.w);
            ax = fmaf(c0, lo16f(u0), ax); ay = fmaf(c0, hi16f(u0), ay);
            ax = fmaf(c1, lo16f(u1), ax); ay = fmaf(c1, hi16f(u1), ay);
            k += 2;
        }
        if (k < cnt) {
            int2 e0 = cpair[p + k];
            unsigned int u0 = hp[(size_t)e0.x * 64 + lane];
            float c0 = __int_as_float(e0.y);
            ax = fmaf(c0, lo16f(u0), ax); ay = fmaf(c0, hi16f(u0), ay);
        }
        if (OUTMODE == 0) {
            float2 o; o.x = ax; o.y = ay;
            ((float2*)out)[(size_t)wid * 64 + lane] = o;
        } else {
            unsigned int u = (unsigned int)(unsigned short)f2bf(ax) |
                             ((unsigned int)(unsigned short)f2bf(ay) << 16);
            ((unsigned int*)out)[(size_t)wid * 64 + lane] = u;
        }
        s0 += ax; q0 = fmaf(ax, ax, q0);
        s1 += ay; q1 = fmaf(ay, ay, q1);

        wid = nxt;
        us = us_n; di = di_n; p = p_n; cnt = cnt_n;
    }

    __shared__ float red[4][256];
    red[0][threadIdx.x] = s0; red[1][threadIdx.x] = q0;
    red[2][threadIdx.x] = s1; red[3][threadIdx.x] = q1;
    __syncthreads();
    if (wv == 0) {
        float a = 0, b = 0, c = 0, d = 0;
#pragma unroll
        for (int w = 0; w < 4; ++w) {
            a += red[0][w * 64 + lane];
            b += red[1][w * 64 + lane];
            c += red[2][w * 64 + lane];
            d += red[3][w * 64 + lane];
        }
        float* pr = partial + (size_t)blockIdx.x * 256;
        pr[2 * lane]       = a;
        pr[2 * lane + 1]   = c;
        pr[128 + 2 * lane]     = b;
        pr[128 + 2 * lane + 1] = d;
    }
}

extern "C" void kernel_launch(void* const* d_in, const int* in_sizes, int n_in,
                              void* d_out, int out_size, void* d_ws, size_t ws_size,
                              hipStream_t stream) {
    const float* x    = (const float*)d_in[0];
    const int*   eidx = (const int*)d_in[1];
    const float* ew   = (const float*)d_in[2];
    const float* dist = (const float*)d_in[3];
    const float* degf = (const float*)d_in[4];
    const float* W1   = (const float*)d_in[5];
    const float* W2   = (const float*)d_in[7];
    const float* bn1g = (const float*)d_in[9];
    const float* bn1b = (const float*)d_in[10];
    const float* bn2g = (const float*)d_in[11];
    const float* bn2b = (const float*)d_in[12];
    const float* Wd   = (const float*)d_in[13];
    const float* bndg = (const float*)d_in[15];
    const float* bndb = (const float*)d_in[16];
    const float* Wg   = (const float*)d_in[17];
    const float* bngg = (const float*)d_in[19];
    const float* bngb = (const float*)d_in[20];
    const float* Wm   = (const float*)d_in[21];
    const float* bm   = (const float*)d_in[22];

    const int n = in_sizes[0] / 128;
    const int e = in_sizes[2];
    const int total = n * 128;
    const int* esrc = eidx;
    const int* edst = eidx + e;

    auto align256 = [](size_t v) { return (v + 255) & ~(size_t)255; };
    char* ws = (char*)d_ws;
    size_t off = 0;
    unsigned short* planeB = (unsigned short*)(ws + off); off += align256((size_t)total * 2);
    unsigned short* planeC = (unsigned short*)(ws + off); off += align256((size_t)total * 2);
    float* aggout = (float*)(ws + off); off += align256((size_t)total * 4);
    int2*  cpair  = (int2*)(ws + off);  off += align256((size_t)e * 8);
    float* partial= (float*)(ws + off); off += align256((size_t)AGG_BLOCKS * 256 * 4);
    float* dinv   = (float*)(ws + off); off += align256((size_t)n * 4);
    int*   counts = (int*)(ws + off);   off += align256((size_t)n * 4);
    int*   offs   = (int*)(ws + off);   off += align256((size_t)n * 4);
    int*   pdx    = (int*)(ws + off);   off += align256((size_t)n * 4);
    int*   pgx    = (int*)(ws + off);   off += align256((size_t)n * 4);
    float* vdc    = (float*)(ws + off); off += align256((size_t)n * 4);
    float* vgc    = (float*)(ws + off); off += align256((size_t)n * 4);
    int*   bsums  = (int*)(ws + off);   off += 4096;
    float* stats  = (float*)(ws + off); off += 4096;
    float* params = (float*)(ws + off); off += 4096;
    float* sortd  = (float*)(ws + off); off += 1024;
    float* sortg  = (float*)(ws + off); off += 1024;
    float4* part4 = (float4*)(ws + off); off += align256((size_t)SSTAT_BLOCKS * 16);
    float* tabd   = (float*)(ws + off); off += align256((size_t)129 * 256 * 4);
    float* tabg   = (float*)(ws + off); off += align256((size_t)129 * 256 * 4);

    // aliases into regions dead until k_aggregate<0> writes aggout:
    unsigned long long* pack64 = (unsigned long long*)aggout;            // NREP*n u64
    int* base = (int*)(aggout + (size_t)NREP * n * 2 + 256);             // NREP*n int
    unsigned short* rank = (unsigned short*)planeC;                      // dead before agg1 output

    float* s1     = stats;
    float* s2     = stats + 256;
    float* scale1 = params;
    float* shift1 = params + 128;
    float* scale2 = params + 256;
    float* shift2 = params + 384;
    float* ad     = params + 512;
    float* ag     = params + 640;
    float* mus    = params + 768;

    const int nbN = (n + 255) / 256;
    const int nbE = (e + 255) / 256;

    // zero the atomic histograms + BN stat accumulators
    hipMemsetAsync(pack64, 0, (size_t)NREP * n * 8, stream);
    hipMemsetAsync(stats, 0, 4096, stream);

    // MEGA1: gemm1 (x@W1 -> planeB bf16) || edge_prep atomics || scalar stats
    k_mega1<<<GEMM_BLOCKS + nbE + SSTAT_BLOCKS, 256, 0, stream>>>(
        edst, ew, pack64, rank, e, n, x, W1, planeB, dist, degf, part4, nbE);

    // scan + branch params
    k_scan1<<<nbN, 256, 0, stream>>>(pack64, counts, offs, bsums, dinv, base, n);
    k_scan2<<<1, 512, 0, stream>>>(bsums, nbN);
    k_scan3b<<<nbN + 1, 256, 0, stream>>>(offs, bsums, n, part4, Wd, bndg, Wg, bngg,
                                          ad, ag, mus, (float)n);

    // CSR fill (+ PWL breakpoint sorts), then PWL tables + per-node index
    k_fill_sort<<<nbE + 2, 256, 0, stream>>>(esrc, edst, ew, rank, dinv, offs, base,
                                             cpair, e, n, nbE, ad, bndb, ag, bngb,
                                             sortd, sortg);
    k_tab_idx<<<258 + 256, 256, 0, stream>>>(ad, bndb, ag, bngb, Wm, sortd, sortg,
                                             tabd, tabg, mus, dist, degf,
                                             pdx, pgx, vdc, vgc, n);

    // layer 1 aggregation (gemm1 already done in MEGA1)
    k_aggregate<1><<<AGG_BLOCKS, 256, 0, stream>>>(planeB, dinv, offs, counts, cpair,
                                                   planeC, partial, n);
    k_colred<<<COLRED_BLOCKS, 256, 0, stream>>>(partial, s1);
    k_bn_params<<<1, 128, 0, stream>>>(s1, bn1g, bn1b, scale1, shift1, (float)n);

    // layer 2: h2 = agg(relu(bn1(h1)) @ W2); grid 2048 for latency-hiding TLP
    gemm_mfma<1><<<2048, 256, 0, stream>>>(planeC, W2, planeB, scale1, shift1, nullptr,
                                           nullptr, nullptr, nullptr, nullptr,
                                           nullptr, nullptr, n);
    k_aggregate<0><<<AGG_BLOCKS, 256, 0, stream>>>(planeB, dinv, offs, counts, cpair,
                                                   aggout, partial, n);
    k_colred<<<COLRED_BLOCKS, 256, 0, stream>>>(partial, s2);
    k_bn_params<<<1, 128, 0, stream>>>(s2, bn2g, bn2b, scale2, shift2, (float)n);

    // final: out = relu(bn2(h2)) @ Wm[0:128] + bm + PWL_d + PWL_g; grid 2048
    gemm_mfma<2><<<2048, 256, 0, stream>>>(aggout, Wm, d_out, scale2, shift2, bm,
                                           pdx, pgx, vdc, vgc, tabd, tabg, n);
}

// Round 11
// 398.777 us; speedup vs baseline: 1.1296x; 1.0676x over previous
//
#include <hip/hip_runtime.h>

#define BN_EPS 1e-5f
#define AGG_BLOCKS 2048
#define COLRED_BLOCKS 64   // AGG_BLOCKS / COLRED_BLOCKS rows each
#define SSTAT_BLOCKS 64
#define GEMM_BLOCKS 1024

typedef __attribute__((ext_vector_type(8))) short short8;
typedef __attribute__((ext_vector_type(4))) float f32x4;

#define MFMA16(a, b, c) __builtin_amdgcn_mfma_f32_16x16x32_bf16(a, b, c, 0, 0, 0)

__device__ __forceinline__ short f2bf(float f) {
    unsigned int u = __float_as_uint(f);
    u = (u + 0x7FFFu + ((u >> 16) & 1u)) >> 16;
    return (short)u;
}
__device__ __forceinline__ float bf2f(short s) {
    return __uint_as_float(((unsigned int)(unsigned short)s) << 16);
}
__device__ __forceinline__ float lo16f(unsigned int u) { return __uint_as_float(u << 16); }
__device__ __forceinline__ float hi16f(unsigned int u) { return __uint_as_float(u & 0xffff0000u); }

// ================= GEMM device body (register-resident W, MFMA) =================
// ASRC 0: A = fp32 raw (x)                      -> C bf16 plane   (2-deep pipeline)
// ASRC 1: A = bf16 raw + BN+ReLU in-register    -> C bf16 plane   (2-deep pipeline)
// ASRC 2: A = fp32 + BN+ReLU + hi/lo split; 3-pass MFMA; bias+PWL epilogue -> C fp32
//         (no prefetch pipeline: +64 VGPR live state costs occupancy — r9 regression.
//          grid MUST stay 1024: blocks amortize the W-fragment prologue — r10 regression at 2048.)
template <int ASRC>
__device__ __forceinline__ void gemm_body(
    const void* __restrict__ Ain, const float* __restrict__ W, void* __restrict__ Cout,
    const float* __restrict__ scale, const float* __restrict__ shift,
    const float* __restrict__ bias,
    const int* __restrict__ pdx, const int* __restrict__ pgx,
    const float* __restrict__ vdc, const float* __restrict__ vgc,
    const float* __restrict__ tabd, const float* __restrict__ tabg,
    int n, int bid, int nb) {
    constexpr bool FINAL = (ASRC == 2);
    const int lane = threadIdx.x & 63;
    const int wave = threadIdx.x >> 6;
    const int l15 = lane & 15, lg = lane >> 4;
    const int cbase = wave * 32;

    short8 wh[4][2], wl[4][2];
#pragma unroll
    for (int kt = 0; kt < 4; ++kt) {
#pragma unroll
        for (int cf = 0; cf < 2; ++cf) {
            int col = cbase + 16 * cf + l15;
            short8 hh, ll;
#pragma unroll
            for (int e = 0; e < 8; ++e) {
                float wv = W[(32 * kt + 8 * lg + e) * 128 + col];
                short hs = f2bf(wv);
                hh[e] = hs;
                if (FINAL) ll[e] = f2bf(wv - bf2f(hs));
            }
            wh[kt][cf] = hh;
            if (FINAL) wl[kt][cf] = ll;
        }
    }

    float4 scr[4][2], shr[4][2];
    if (ASRC == 1) {
#pragma unroll
        for (int kt = 0; kt < 4; ++kt) {
            scr[kt][0] = *(const float4*)&scale[32 * kt + 8 * lg];
            scr[kt][1] = *(const float4*)&scale[32 * kt + 8 * lg + 4];
            shr[kt][0] = *(const float4*)&shift[32 * kt + 8 * lg];
            shr[kt][1] = *(const float4*)&shift[32 * kt + 8 * lg + 4];
        }
    }

    float b0 = 0.f, b1 = 0.f;
    if (FINAL) { b0 = bias[cbase + l15]; b1 = bias[cbase + 16 + l15]; }

    const int ntiles = (n + 15) >> 4;

    short8 ah[4], al[4], nh[4];
    auto loada = [&](int t, short8* H, short8* L) {
        int row = t * 16 + l15;
        if (row >= n) row = n - 1;
        if (ASRC == 0) {
            const float* p = (const float*)Ain + (size_t)row * 128 + 8 * lg;
#pragma unroll
            for (int kt = 0; kt < 4; ++kt) {
                float4 u = *(const float4*)(p + 32 * kt);
                float4 v = *(const float4*)(p + 32 * kt + 4);
                short8 h;
                h[0] = f2bf(u.x); h[1] = f2bf(u.y); h[2] = f2bf(u.z); h[3] = f2bf(u.w);
                h[4] = f2bf(v.x); h[5] = f2bf(v.y); h[6] = f2bf(v.z); h[7] = f2bf(v.w);
                H[kt] = h;
            }
        } else if (ASRC == 1) {
            const unsigned short* p = (const unsigned short*)Ain + (size_t)row * 128 + 8 * lg;
#pragma unroll
            for (int kt = 0; kt < 4; ++kt) {
                short8 s = *(const short8*)(p + 32 * kt);
                short8 h;
#pragma unroll
                for (int e = 0; e < 8; ++e) {
                    float sc = (e < 4) ? ((const float*)&scr[kt][0])[e] : ((const float*)&scr[kt][1])[e - 4];
                    float sh = (e < 4) ? ((const float*)&shr[kt][0])[e] : ((const float*)&shr[kt][1])[e - 4];
                    float f = fmaxf(0.0f, fmaf(bf2f(s[e]), sc, sh));
                    h[e] = f2bf(f);
                }
                H[kt] = h;
            }
        } else {
            const float* p = (const float*)Ain + (size_t)row * 128 + 8 * lg;
#pragma unroll
            for (int kt = 0; kt < 4; ++kt) {
                float4 u = *(const float4*)(p + 32 * kt);
                float4 v = *(const float4*)(p + 32 * kt + 4);
                float4 sa = *(const float4*)&scale[32 * kt + 8 * lg];
                float4 sb = *(const float4*)&scale[32 * kt + 8 * lg + 4];
                float4 ta = *(const float4*)&shift[32 * kt + 8 * lg];
                float4 tb = *(const float4*)&shift[32 * kt + 8 * lg + 4];
                float f[8];
                f[0] = fmaxf(0.f, fmaf(u.x, sa.x, ta.x));
                f[1] = fmaxf(0.f, fmaf(u.y, sa.y, ta.y));
                f[2] = fmaxf(0.f, fmaf(u.z, sa.z, ta.z));
                f[3] = fmaxf(0.f, fmaf(u.w, sa.w, ta.w));
                f[4] = fmaxf(0.f, fmaf(v.x, sb.x, tb.x));
                f[5] = fmaxf(0.f, fmaf(v.y, sb.y, tb.y));
                f[6] = fmaxf(0.f, fmaf(v.z, sb.z, tb.z));
                f[7] = fmaxf(0.f, fmaf(v.w, sb.w, tb.w));
                short8 h, l;
#pragma unroll
                for (int e = 0; e < 8; ++e) {
                    short hs = f2bf(f[e]);
                    h[e] = hs;
                    l[e] = f2bf(f[e] - bf2f(hs));
                }
                H[kt] = h;
                L[kt] = l;
            }
        }
    };

    int tile = bid;
    if (!FINAL && tile < ntiles) loada(tile, ah, nullptr);
    for (; tile < ntiles; tile += nb) {
        if (!FINAL) {
            int nx = tile + nb;
            if (nx < ntiles) loada(nx, nh, nullptr);   // 2-deep pipeline
        } else {
            loada(tile, ah, al);
        }

        f32x4 acc0 = {0.f, 0.f, 0.f, 0.f};
        f32x4 acc1 = {0.f, 0.f, 0.f, 0.f};
#pragma unroll
        for (int kt = 0; kt < 4; ++kt) {
            acc0 = MFMA16(ah[kt], wh[kt][0], acc0);
            acc1 = MFMA16(ah[kt], wh[kt][1], acc1);
        }
        if (FINAL) {
#pragma unroll
            for (int kt = 0; kt < 4; ++kt) {
                acc0 = MFMA16(al[kt], wh[kt][0], acc0);
                acc1 = MFMA16(al[kt], wh[kt][1], acc1);
            }
#pragma unroll
            for (int kt = 0; kt < 4; ++kt) {
                acc0 = MFMA16(ah[kt], wl[kt][0], acc0);
                acc1 = MFMA16(ah[kt], wl[kt][1], acc1);
            }
        }

        int rbase = tile * 16;
        if constexpr (!FINAL) {
            unsigned short* C = (unsigned short*)Cout;
#pragma unroll
            for (int r = 0; r < 4; ++r) {
                int row = rbase + lg * 4 + r;
                if (row < n) {
                    C[(size_t)row * 128 + cbase + l15]      = (unsigned short)f2bf(acc0[r]);
                    C[(size_t)row * 128 + cbase + 16 + l15] = (unsigned short)f2bf(acc1[r]);
                }
            }
        } else {
            float* C = (float*)Cout;
#pragma unroll
            for (int r = 0; r < 4; ++r) {
                int row = rbase + lg * 4 + r;
                int rc = row < n ? row : n - 1;
                float vd = vdc[rc], vg = vgc[rc];
                int pd = pdx[rc] * 256, pg = pgx[rc] * 256;
                int c0 = cbase + l15, c1 = cbase + 16 + l15;
                float v0 = acc0[r] + b0, v1 = acc1[r] + b1;
                v0 = fmaf(tabd[pd + c0], vd, v0) + tabd[pd + 128 + c0];
                v1 = fmaf(tabd[pd + c1], vd, v1) + tabd[pd + 128 + c1];
                v0 = fmaf(tabg[pg + c0], vg, v0) + tabg[pg + 128 + c0];
                v1 = fmaf(tabg[pg + c1], vg, v1) + tabg[pg + 128 + c1];
                if (row < n) {
                    C[(size_t)row * 128 + c0] = v0;
                    C[(size_t)row * 128 + c1] = v1;
                }
            }
        }
        if (!FINAL) {
#pragma unroll
            for (int kt = 0; kt < 4; ++kt) ah[kt] = nh[kt];
        }
    }
}

template <int ASRC>
__global__ __launch_bounds__(256) void gemm_mfma(
    const void* __restrict__ Ain, const float* __restrict__ W, void* __restrict__ Cout,
    const float* __restrict__ scale, const float* __restrict__ shift,
    const float* __restrict__ bias,
    const int* __restrict__ pdx, const int* __restrict__ pgx,
    const float* __restrict__ vdc, const float* __restrict__ vgc,
    const float* __restrict__ tabd, const float* __restrict__ tabg, int n) {
    gemm_body<ASRC>(Ain, W, Cout, scale, shift, bias, pdx, pgx, vdc, vgc, tabd, tabg,
                    n, blockIdx.x, gridDim.x);
}

// ================= MEGA1: gemm1 (blocks 0..GB) + edge_prep + scalar_stats =================
// pack64[d] accumulates (count << 54) | sum(ew * 2^40); rank from the atomic return.
// (single histogram: 8-way replication measured zero benefit — atomic-op-rate bound, r7)
__global__ __launch_bounds__(256) void k_mega1(
    const int* __restrict__ dst, const float* __restrict__ ew,
    unsigned long long* __restrict__ pack64, unsigned short* __restrict__ rank,
    int e, int n,
    const float* __restrict__ x, const float* __restrict__ W1, void* __restrict__ planeB,
    const float* __restrict__ df, const float* __restrict__ gf,
    float4* __restrict__ partial4, int nbE) {
    if (blockIdx.x < GEMM_BLOCKS) {
        gemm_body<0>(x, W1, planeB, nullptr, nullptr, nullptr,
                     nullptr, nullptr, nullptr, nullptr, nullptr, nullptr,
                     n, blockIdx.x, GEMM_BLOCKS);
        return;
    }
    int bid = blockIdx.x - GEMM_BLOCKS;
    if (bid < nbE) {
        int i = bid * 256 + threadIdx.x;
        if (i < e) {
            int d = dst[i];
            unsigned long long fx = (unsigned long long)(ew[i] * 1.099511627776e12f);  // 2^40
            unsigned long long old = atomicAdd(&pack64[d], (1ull << 54) | fx);
            rank[i] = (unsigned short)(old >> 54);
        }
        return;
    }
    // scalar-stats role
    int sb = bid - nbE;
    float sd = 0, sd2 = 0, sg = 0, sg2 = 0;
    for (int i = sb * 256 + threadIdx.x; i < n; i += SSTAT_BLOCKS * 256) {
        float a = df[i], b = gf[i];
        sd += a; sd2 += a * a; sg += b; sg2 += b * b;
    }
    for (int off = 32; off > 0; off >>= 1) {
        sd  += __shfl_down(sd, off, 64);
        sd2 += __shfl_down(sd2, off, 64);
        sg  += __shfl_down(sg, off, 64);
        sg2 += __shfl_down(sg2, off, 64);
    }
    __shared__ float4 wred[4];
    int lane = threadIdx.x & 63, wave = threadIdx.x >> 6;
    if (lane == 0) { float4 v; v.x = sd; v.y = sd2; v.z = sg; v.w = sg2; wred[wave] = v; }
    __syncthreads();
    if (threadIdx.x == 0) {
        float4 a = wred[0], b = wred[1], c = wred[2], d = wred[3];
        float4 o;
        o.x = a.x + b.x + c.x + d.x;
        o.y = a.y + b.y + c.y + d.y;
        o.z = a.z + b.z + c.z + d.z;
        o.w = a.w + b.w + c.w + d.w;
        partial4[sb] = o;
    }
}

// ---------------- scan: counts/dinv from pack64, block-scan offs ----------------
__global__ void k_scan1(const unsigned long long* __restrict__ pack64,
                        int* counts, int* offs, int* bsums, float* dinv, int n) {
    __shared__ int tmp[256];
    int t = threadIdx.x;
    int i = blockIdx.x * 256 + t;
    int v = 0;
    if (i < n) {
        unsigned long long p = pack64[i];
        v = (int)(p >> 54);
        float deg = 1.0f + (float)(p & ((1ull << 54) - 1ull)) * 9.094947017729282e-13f; // 2^-40
        dinv[i] = rsqrtf(deg);
        counts[i] = v;
    }
    tmp[t] = v;
    __syncthreads();
    for (int d = 1; d < 256; d <<= 1) {
        int add = (t >= d) ? tmp[t - d] : 0;
        __syncthreads();
        tmp[t] += add;
        __syncthreads();
    }
    if (i < n) offs[i] = tmp[t] - v;
    if (t == 255) bsums[blockIdx.x] = tmp[255];
}

__global__ void k_scan2(int* bsums, int nb) {
    __shared__ int tmp[512];
    int t = threadIdx.x;
    int v = (t < nb) ? bsums[t] : 0;
    tmp[t] = v;
    __syncthreads();
    for (int d = 1; d < 512; d <<= 1) {
        int add = (t >= d) ? tmp[t - d] : 0;
        __syncthreads();
        tmp[t] += add;
        __syncthreads();
    }
    if (t < nb) bsums[t] = tmp[t] - v;
}

// ---------------- scan3 + branch-params (last block) ----------------
__global__ void k_scan3b(int* offs, const int* __restrict__ bsums, int n,
                         const float4* __restrict__ partial4,
                         const float* __restrict__ Wd, const float* __restrict__ bndg,
                         const float* __restrict__ Wg, const float* __restrict__ bngg,
                         float* ad, float* ag, float* mus, float fn) {
    if (blockIdx.x + 1 < gridDim.x) {
        int i = blockIdx.x * blockDim.x + threadIdx.x;
        if (i < n) offs[i] += bsums[blockIdx.x];
        return;
    }
    __shared__ float scal[4];
    int j = threadIdx.x;
    if (j < 4) {
        float acc = 0.0f;
        for (int b = 0; b < SSTAT_BLOCKS; ++b) acc += ((const float*)&partial4[b])[j];
        scal[j] = acc;
    }
    __syncthreads();
    if (j < 128) {
        float mu_d = scal[0] / fn, var_d = scal[1] / fn - mu_d * mu_d;
        float mu_g = scal[2] / fn, var_g = scal[3] / fn - mu_g * mu_g;
        var_d = fmaxf(var_d, 0.0f);
        var_g = fmaxf(var_g, 0.0f);
        ad[j] = Wd[j] * bndg[j] * rsqrtf(var_d * Wd[j] * Wd[j] + BN_EPS);
        ag[j] = Wg[j] * bngg[j] * rsqrtf(var_g * Wg[j] * Wg[j] + BN_EPS);
        if (j == 0) { mus[0] = mu_d; mus[1] = mu_g; }
    }
}

// ---------------- CSR fill (+ 2 sort blocks at the end) ----------------
__global__ void k_fill_sort(const int* __restrict__ src, const int* __restrict__ dst,
                            const float* __restrict__ ew, const unsigned short* __restrict__ rank,
                            const float* __restrict__ dinv, const int* __restrict__ offs,
                            int2* __restrict__ cpair, int e, int n, int nbE,
                            const float* __restrict__ ad, const float* __restrict__ bndb,
                            const float* __restrict__ ag, const float* __restrict__ bngb,
                            float* __restrict__ sortd, float* __restrict__ sortg) {
    if (blockIdx.x < (unsigned)nbE) {
        int i = blockIdx.x * 256 + threadIdx.x;
        if (i < e) {
            int s = src[i], d = dst[i];
            float c = dinv[s] * ew[i] * dinv[d];
            int p = offs[d] + (int)rank[i];
            int2 pr;
            pr.x = s;
            pr.y = __float_as_int(c);
            cpair[p] = pr;
        }
        return;
    }
    int which = blockIdx.x - nbE;   // 0 = dist, 1 = degree
    const float* a = which ? ag : ad;
    const float* b = which ? bngb : bndb;
    float* sorted = which ? sortg : sortd;
    __shared__ float t[128];
    int j = threadIdx.x;
    if (j < 128) {
        float aj = a[j], bj = b[j];
        float tj;
        if (aj != 0.0f) tj = -bj / aj;
        else tj = (bj > 0.0f) ? -1e30f : 1e30f;
        t[j] = tj;
    }
    __syncthreads();
    if (j < 128) {
        float tj = t[j];
        int rank_ = 0;
        for (int k = 0; k < 128; k++) {
            float tk = t[k];
            if (tk < tj || (tk == tj && k < j)) rank_++;
        }
        sorted[rank_] = tj;
    }
}

// ---------------- PWL tables (blocks 0..257) + per-node interval index (rest) ----------------
__global__ __launch_bounds__(256) void k_tab_idx(
    const float* __restrict__ ad, const float* __restrict__ bndb,
    const float* __restrict__ ag, const float* __restrict__ bngb,
    const float* __restrict__ Wm, const float* __restrict__ sortd,
    const float* __restrict__ sortg, float* __restrict__ tabd, float* __restrict__ tabg,
    const float* __restrict__ mus, const float* __restrict__ dist,
    const float* __restrict__ degf,
    int* __restrict__ pdx, int* __restrict__ pgx,
    float* __restrict__ vdc, float* __restrict__ vgc, int n) {
    if (blockIdx.x < 258) {
        int which = blockIdx.x >= 129;
        int p = blockIdx.x - which * 129;
        int c = threadIdx.x;
        if (c >= 128) return;
        const float* a = which ? ag : ad;
        const float* b = which ? bngb : bndb;
        const float* sorted = which ? sortg : sortd;
        const float* Wm2 = Wm + (which ? 256 : 128) * 128;
        float* tab = which ? tabg : tabd;
        float lo = (p == 0) ? -1e30f : sorted[p - 1];
        float hi = (p == 128) ? 1e30f : sorted[p];
        float vm = 0.5f * lo + 0.5f * hi;
        float As = 0.0f, Bs = 0.0f;
        for (int j = 0; j < 128; j++) {
            float aj = a[j], bj = b[j];
            if (fmaf(aj, vm, bj) > 0.0f) {
                float w = Wm2[j * 128 + c];
                As = fmaf(aj, w, As);
                Bs = fmaf(bj, w, Bs);
            }
        }
        tab[p * 256 + c] = As;
        tab[p * 256 + 128 + c] = Bs;
        return;
    }
    // per-node interval index role (grid-stride)
    __shared__ float sd[128], sg[128];
    if (threadIdx.x < 128) {
        sd[threadIdx.x] = sortd[threadIdx.x];
        sg[threadIdx.x] = sortg[threadIdx.x];
    }
    __syncthreads();
    int nb = gridDim.x - 258;
    float m0 = mus[0], m1 = mus[1];
    for (int i = (blockIdx.x - 258) * 256 + threadIdx.x; i < n; i += nb * 256) {
        float vd = dist[i] - m0, vg = degf[i] - m1;
        int lo = 0, hi = 128;
        while (lo < hi) { int m = (lo + hi) >> 1; if (sd[m] < vd) lo = m + 1; else hi = m; }
        pdx[i] = lo; vdc[i] = vd;
        lo = 0; hi = 128;
        while (lo < hi) { int m = (lo + hi) >> 1; if (sg[m] < vg) lo = m + 1; else hi = m; }
        pgx[i] = lo; vgc[i] = vg;
    }
}

// ---------------- column-partial reduce -> stats (64 blocks) ----------------
__global__ void k_colred(const float* __restrict__ partial, float* stats) {
    int tid = threadIdx.x;
    int b = blockIdx.x;
    const int rows = AGG_BLOCKS / COLRED_BLOCKS;
    float acc = 0.0f;
    for (int j = b * rows; j < (b + 1) * rows; ++j) acc += partial[j * 256 + tid];
    atomicAdd(&stats[tid], acc);
}

// ---------------- BN scale/shift ----------------
__global__ void k_bn_params(const float* __restrict__ stats, const float* __restrict__ g,
                            const float* __restrict__ b, float* scale, float* shift, float n) {
    int j = threadIdx.x;
    float mean = stats[j] / n;
    float var = stats[128 + j] / n - mean * mean;
    var = fmaxf(var, 0.0f);
    float sc = g[j] * rsqrtf(var + BN_EPS);
    scale[j] = sc;
    shift[j] = b[j] - mean * sc;
}

// ---------------- aggregation (bf16 gather) + fused BN col-stats ----------------
// OUTMODE 0: write fp32 float2;  OUTMODE 1: write packed bf16
template <int OUTMODE>
__global__ __launch_bounds__(256) void k_aggregate(
    const unsigned short* __restrict__ h, const float* __restrict__ dinv,
    const int* __restrict__ offs, const int* __restrict__ counts,
    const int2* __restrict__ cpair, void* __restrict__ out,
    float* __restrict__ partial, int n) {
    int lane = threadIdx.x & 63;
    int wv = __builtin_amdgcn_readfirstlane(threadIdx.x >> 6);
    int gw = blockIdx.x * 4 + wv;
    int nw = gridDim.x * 4;
    const unsigned int* hp = (const unsigned int*)h;

    float s0 = 0, q0 = 0, s1 = 0, q1 = 0;

    int wid = gw;
    unsigned int us = 0; float di = 0.f; int p = 0, cnt = 0;
    if (wid < n) {
        us = hp[(size_t)wid * 64 + lane];
        di = dinv[wid];
        p = __builtin_amdgcn_readfirstlane(offs[wid]);
        cnt = __builtin_amdgcn_readfirstlane(counts[wid]);
    }
    while (wid < n) {
        int nxt = wid + nw;
        unsigned int us_n = 0; float di_n = 0.f; int p_n = 0, cnt_n = 0;
        if (nxt < n) {
            us_n = hp[(size_t)nxt * 64 + lane];
            di_n = dinv[nxt];
            p_n = __builtin_amdgcn_readfirstlane(offs[nxt]);
            cnt_n = __builtin_amdgcn_readfirstlane(counts[nxt]);
        }

        float d2 = di * di;
        float ax = d2 * lo16f(us), ay = d2 * hi16f(us);
        int k = 0;
        for (; k + 8 <= cnt; k += 8) {
            int4 ea = *(const int4*)&cpair[p + k];
            int4 eb = *(const int4*)&cpair[p + k + 2];
            int4 ec = *(const int4*)&cpair[p + k + 4];
            int4 ed = *(const int4*)&cpair[p + k + 6];
            unsigned int u0 = hp[(size_t)ea.x * 64 + lane];
            unsigned int u1 = hp[(size_t)ea.z * 64 + lane];
            unsigned int u2 = hp[(size_t)eb.x * 64 + lane];
            unsigned int u3 = hp[(size_t)eb.z * 64 + lane];
            unsigned int u4 = hp[(size_t)ec.x * 64 + lane];
            unsigned int u5 = hp[(size_t)ec.z * 64 + lane];
            unsigned int u6 = hp[(size_t)ed.x * 64 + lane];
            unsigned int u7 = hp[(size_t)ed.z * 64 + lane];
            float c0 = __int_as_float(ea.y), c1 = __int_as_float(ea.w);
            float c2 = __int_as_float(eb.y), c3 = __int_as_float(eb.w);
            float c4 = __int_as_float(ec.y), c5 = __int_as_float(ec.w);
            float c6 = __int_as_float(ed.y), c7 = __int_as_float(ed.w);
            ax = fmaf(c0, lo16f(u0), ax); ay = fmaf(c0, hi16f(u0), ay);
            ax = fmaf(c1, lo16f(u1), ax); ay = fmaf(c1, hi16f(u1), ay);
            ax = fmaf(c2, lo16f(u2), ax); ay = fmaf(c2, hi16f(u2), ay);
            ax = fmaf(c3, lo16f(u3), ax); ay = fmaf(c3, hi16f(u3), ay);
            ax = fmaf(c4, lo16f(u4), ax); ay = fmaf(c4, hi16f(u4), ay);
            ax = fmaf(c5, lo16f(u5), ax); ay = fmaf(c5, hi16f(u5), ay);
            ax = fmaf(c6, lo16f(u6), ax); ay = fmaf(c6, hi16f(u6), ay);
            ax = fmaf(c7, lo16f(u7), ax); ay = fmaf(c7, hi16f(u7), ay);
        }
        if (k + 4 <= cnt) {
            int4 ea = *(const int4*)&cpair[p + k];
            int4 eb = *(const int4*)&cpair[p + k + 2];
            unsigned int u0 = hp[(size_t)ea.x * 64 + lane];
            unsigned int u1 = hp[(size_t)ea.z * 64 + lane];
            unsigned int u2 = hp[(size_t)eb.x * 64 + lane];
            unsigned int u3 = hp[(size_t)eb.z * 64 + lane];
            float c0 = __int_as_float(ea.y), c1 = __int_as_float(ea.w);
            float c2 = __int_as_float(eb.y), c3 = __int_as_float(eb.w);
            ax = fmaf(c0, lo16f(u0), ax); ay = fmaf(c0, hi16f(u0), ay);
            ax = fmaf(c1, lo16f(u1), ax); ay = fmaf(c1, hi16f(u1), ay);
            ax = fmaf(c2, lo16f(u2), ax); ay = fmaf(c2, hi16f(u2), ay);
            ax = fmaf(c3, lo16f(u3), ax); ay = fmaf(c3, hi16f(u3), ay);
            k += 4;
        }
        if (k + 2 <= cnt) {
            int4 ee = *(const int4*)&cpair[p + k];
            unsigned int u0 = hp[(size_t)ee.x * 64 + lane];
            unsigned int u1 = hp[(size_t)ee.z * 64 + lane];
            float c0 = __int_as_float(ee.y), c1 = __int_as_float(ee.w);
            ax = fmaf(c0, lo16f(u0), ax); ay = fmaf(c0, hi16f(u0), ay);
            ax = fmaf(c1, lo16f(u1), ax); ay = fmaf(c1, hi16f(u1), ay);
            k += 2;
        }
        if (k < cnt) {
            int2 e0 = cpair[p + k];
            unsigned int u0 = hp[(size_t)e0.x * 64 + lane];
            float c0 = __int_as_float(e0.y);
            ax = fmaf(c0, lo16f(u0), ax); ay = fmaf(c0, hi16f(u0), ay);
        }
        if (OUTMODE == 0) {
            float2 o; o.x = ax; o.y = ay;
            ((float2*)out)[(size_t)wid * 64 + lane] = o;
        } else {
            unsigned int u = (unsigned int)(unsigned short)f2bf(ax) |
                             ((unsigned int)(unsigned short)f2bf(ay) << 16);
            ((unsigned int*)out)[(size_t)wid * 64 + lane] = u;
        }
        s0 += ax; q0 = fmaf(ax, ax, q0);
        s1 += ay; q1 = fmaf(ay, ay, q1);

        wid = nxt;
        us = us_n; di = di_n; p = p_n; cnt = cnt_n;
    }

    __shared__ float red[4][256];
    red[0][threadIdx.x] = s0; red[1][threadIdx.x] = q0;
    red[2][threadIdx.x] = s1; red[3][threadIdx.x] = q1;
    __syncthreads();
    if (wv == 0) {
        float a = 0, b = 0, c = 0, d = 0;
#pragma unroll
        for (int w = 0; w < 4; ++w) {
            a += red[0][w * 64 + lane];
            b += red[1][w * 64 + lane];
            c += red[2][w * 64 + lane];
            d += red[3][w * 64 + lane];
        }
        float* pr = partial + (size_t)blockIdx.x * 256;
        pr[2 * lane]       = a;
        pr[2 * lane + 1]   = c;
        pr[128 + 2 * lane]     = b;
        pr[128 + 2 * lane + 1] = d;
    }
}

extern "C" void kernel_launch(void* const* d_in, const int* in_sizes, int n_in,
                              void* d_out, int out_size, void* d_ws, size_t ws_size,
                              hipStream_t stream) {
    const float* x    = (const float*)d_in[0];
    const int*   eidx = (const int*)d_in[1];
    const float* ew   = (const float*)d_in[2];
    const float* dist = (const float*)d_in[3];
    const float* degf = (const float*)d_in[4];
    const float* W1   = (const float*)d_in[5];
    const float* W2   = (const float*)d_in[7];
    const float* bn1g = (const float*)d_in[9];
    const float* bn1b = (const float*)d_in[10];
    const float* bn2g = (const float*)d_in[11];
    const float* bn2b = (const float*)d_in[12];
    const float* Wd   = (const float*)d_in[13];
    const float* bndg = (const float*)d_in[15];
    const float* bndb = (const float*)d_in[16];
    const float* Wg   = (const float*)d_in[17];
    const float* bngg = (const float*)d_in[19];
    const float* bngb = (const float*)d_in[20];
    const float* Wm   = (const float*)d_in[21];
    const float* bm   = (const float*)d_in[22];

    const int n = in_sizes[0] / 128;
    const int e = in_sizes[2];
    const int total = n * 128;
    const int* esrc = eidx;
    const int* edst = eidx + e;

    auto align256 = [](size_t v) { return (v + 255) & ~(size_t)255; };
    char* ws = (char*)d_ws;
    size_t off = 0;
    unsigned short* planeB = (unsigned short*)(ws + off); off += align256((size_t)total * 2);
    unsigned short* planeC = (unsigned short*)(ws + off); off += align256((size_t)total * 2);
    float* aggout = (float*)(ws + off); off += align256((size_t)total * 4);
    int2*  cpair  = (int2*)(ws + off);  off += align256((size_t)e * 8);
    float* partial= (float*)(ws + off); off += align256((size_t)AGG_BLOCKS * 256 * 4);
    float* dinv   = (float*)(ws + off); off += align256((size_t)n * 4);
    int*   counts = (int*)(ws + off);   off += align256((size_t)n * 4);
    int*   offs   = (int*)(ws + off);   off += align256((size_t)n * 4);
    int*   pdx    = (int*)(ws + off);   off += align256((size_t)n * 4);
    int*   pgx    = (int*)(ws + off);   off += align256((size_t)n * 4);
    float* vdc    = (float*)(ws + off); off += align256((size_t)n * 4);
    float* vgc    = (float*)(ws + off); off += align256((size_t)n * 4);
    int*   bsums  = (int*)(ws + off);   off += 4096;
    float* stats  = (float*)(ws + off); off += 4096;
    float* params = (float*)(ws + off); off += 4096;
    float* sortd  = (float*)(ws + off); off += 1024;
    float* sortg  = (float*)(ws + off); off += 1024;
    float4* part4 = (float4*)(ws + off); off += align256((size_t)SSTAT_BLOCKS * 16);
    float* tabd   = (float*)(ws + off); off += align256((size_t)129 * 256 * 4);
    float* tabg   = (float*)(ws + off); off += align256((size_t)129 * 256 * 4);

    // aliases into regions dead until k_aggregate<0> writes aggout:
    unsigned long long* pack64 = (unsigned long long*)aggout;            // n u64 = 0.8 MB
    unsigned short* rank = (unsigned short*)planeC;                      // dead before agg1 output

    float* s1     = stats;
    float* s2     = stats + 256;
    float* scale1 = params;
    float* shift1 = params + 128;
    float* scale2 = params + 256;
    float* shift2 = params + 384;
    float* ad     = params + 512;
    float* ag     = params + 640;
    float* mus    = params + 768;

    const int nbN = (n + 255) / 256;
    const int nbE = (e + 255) / 256;

    // zero the atomic histogram + BN stat accumulators
    hipMemsetAsync(pack64, 0, (size_t)n * 8, stream);
    hipMemsetAsync(stats, 0, 4096, stream);

    // MEGA1: gemm1 (x@W1 -> planeB bf16) || edge_prep atomics || scalar stats
    k_mega1<<<GEMM_BLOCKS + nbE + SSTAT_BLOCKS, 256, 0, stream>>>(
        edst, ew, pack64, rank, e, n, x, W1, planeB, dist, degf, part4, nbE);

    // scan + branch params
    k_scan1<<<nbN, 256, 0, stream>>>(pack64, counts, offs, bsums, dinv, n);
    k_scan2<<<1, 512, 0, stream>>>(bsums, nbN);
    k_scan3b<<<nbN + 1, 256, 0, stream>>>(offs, bsums, n, part4, Wd, bndg, Wg, bngg,
                                          ad, ag, mus, (float)n);

    // CSR fill (+ PWL breakpoint sorts), then PWL tables + per-node index
    k_fill_sort<<<nbE + 2, 256, 0, stream>>>(esrc, edst, ew, rank, dinv, offs,
                                             cpair, e, n, nbE, ad, bndb, ag, bngb,
                                             sortd, sortg);
    k_tab_idx<<<258 + 256, 256, 0, stream>>>(ad, bndb, ag, bngb, Wm, sortd, sortg,
                                             tabd, tabg, mus, dist, degf,
                                             pdx, pgx, vdc, vgc, n);

    // layer 1 aggregation (gemm1 already done in MEGA1)
    k_aggregate<1><<<AGG_BLOCKS, 256, 0, stream>>>(planeB, dinv, offs, counts, cpair,
                                                   planeC, partial, n);
    k_colred<<<COLRED_BLOCKS, 256, 0, stream>>>(partial, s1);
    k_bn_params<<<1, 128, 0, stream>>>(s1, bn1g, bn1b, scale1, shift1, (float)n);

    // layer 2: h2 = agg(relu(bn1(h1)) @ W2)
    gemm_mfma<1><<<1024, 256, 0, stream>>>(planeC, W2, planeB, scale1, shift1, nullptr,
                                           nullptr, nullptr, nullptr, nullptr,
                                           nullptr, nullptr, n);
    k_aggregate<0><<<AGG_BLOCKS, 256, 0, stream>>>(planeB, dinv, offs, counts, cpair,
                                                   aggout, partial, n);
    k_colred<<<COLRED_BLOCKS, 256, 0, stream>>>(partial, s2);
    k_bn_params<<<1, 128, 0, stream>>>(s2, bn2g, bn2b, scale2, shift2, (float)n);

    // final: out = relu(bn2(h2)) @ Wm[0:128] + bm + PWL_d + PWL_g
    gemm_mfma<2><<<1024, 256, 0, stream>>>(aggout, Wm, d_out, scale2, shift2, bm,
                                           pdx, pgx, vdc, vgc, tabd, tabg, n);
}